// Round 2
// baseline (4603.877 us; speedup 1.0000x reference)
//
#include <hip/hip_runtime.h>
#include <math.h>

#define B_ 128
#define T_ 32
#define F_ 2048
#define H_ 1024
#define L_ 20
#define WV_ 300

__device__ __forceinline__ float sigf(float x) { return 1.0f / (1.0f + expf(-x)); }

// C[M,N] = A[M,K] @ W[K,N] (+bias)
// MODE_A: 0 = linear rows (lda), 1 = frames mapping (row r=t*B+b -> frames[b,t,:])
// MODE_C: 0 = linear (ldc), 1 = proj scatter: r=l*B+b -> out[b*L*WV + l*WV + n]
template<int BM, int BN, int TM, int TN, int MODE_A, int MODE_C>
__global__ __launch_bounds__(256)
void gemm_f32(int M, int N, int K,
              const float* __restrict__ A, int lda,
              const float* __restrict__ W, int ldw,
              const float* __restrict__ bias,
              float* __restrict__ C, int ldc)
{
    constexpr int BK = 16;
    __shared__ float As[BK][BM];   // stored transposed: As[k][m]
    __shared__ float Bs[BK][BN];

    const int tid = threadIdx.x;
    const int bm = blockIdx.x * BM;
    const int bn = blockIdx.y * BN;

    const int tx = tid % (BN / TN);
    const int ty = tid / (BN / TN);
    const int row0 = ty * TM;
    const int col0 = tx * TN;

    float acc[TM][TN];
#pragma unroll
    for (int i = 0; i < TM; ++i)
#pragma unroll
        for (int j = 0; j < TN; ++j) acc[i][j] = 0.0f;

    // per-thread A-load coordinates (BM=64: one float4 per thread)
    const int ar = tid / (BK / 4);          // 0..63
    const int ak = (tid % (BK / 4)) * 4;    // 0,4,8,12
    const float* arow;
    {
        int gr = bm + ar;
        if (MODE_A == 1) {
            int t = gr / B_;
            int b = gr % B_;
            arow = A + ((size_t)b * T_ + t) * F_;
        } else {
            arow = A + (size_t)gr * lda;
        }
    }

    for (int k0 = 0; k0 < K; k0 += BK) {
        // ---- load A tile (BM x BK), store transposed ----
        {
            int gk = k0 + ak;
            float4 v;
            if (gk + 4 <= K) {
                v = *(const float4*)(arow + gk);
            } else {
                v.x = (gk + 0 < K) ? arow[gk + 0] : 0.0f;
                v.y = (gk + 1 < K) ? arow[gk + 1] : 0.0f;
                v.z = (gk + 2 < K) ? arow[gk + 2] : 0.0f;
                v.w = (gk + 3 < K) ? arow[gk + 3] : 0.0f;
            }
            As[ak + 0][ar] = v.x;
            As[ak + 1][ar] = v.y;
            As[ak + 2][ar] = v.z;
            As[ak + 3][ar] = v.w;
        }
        // ---- load B tile (BK x BN) ----
        if constexpr (BN == 64) {
            int kl = tid / 16;
            int cq = (tid % 16) * 4;
            int gk = k0 + kl;
            int gc = bn + cq;
            float4 v = make_float4(0.f, 0.f, 0.f, 0.f);
            if (gk < K) {
                const float* wr = W + (size_t)gk * ldw;
                if (gc + 4 <= N) {
                    v = *(const float4*)(wr + gc);
                } else {
                    v.x = (gc + 0 < N) ? wr[gc + 0] : 0.f;
                    v.y = (gc + 1 < N) ? wr[gc + 1] : 0.f;
                    v.z = (gc + 2 < N) ? wr[gc + 2] : 0.f;
                    v.w = (gc + 3 < N) ? wr[gc + 3] : 0.f;
                }
            }
            *(float4*)&Bs[kl][cq] = v;
        } else { // BN == 32
            int kl = tid / 16;
            int cq = (tid % 16) * 2;
            int gk = k0 + kl;
            int gc = bn + cq;
            float2 v = make_float2(0.f, 0.f);
            if (gk < K) {
                const float* wr = W + (size_t)gk * ldw;
                v.x = (gc + 0 < N) ? wr[gc + 0] : 0.f;
                v.y = (gc + 1 < N) ? wr[gc + 1] : 0.f;
            }
            *(float2*)&Bs[kl][cq] = v;
        }
        __syncthreads();

#pragma unroll
        for (int k = 0; k < BK; ++k) {
            float4 av = *(const float4*)&As[k][row0];
            float a_[4] = {av.x, av.y, av.z, av.w};
            if constexpr (TN == 4) {
                float4 bv = *(const float4*)&Bs[k][col0];
                float b_[4] = {bv.x, bv.y, bv.z, bv.w};
#pragma unroll
                for (int i = 0; i < TM; ++i)
#pragma unroll
                    for (int j = 0; j < 4; ++j)
                        acc[i][j] = fmaf(a_[i], b_[j], acc[i][j]);
            } else {
                float2 bv = *(const float2*)&Bs[k][col0];
                float b_[2] = {bv.x, bv.y};
#pragma unroll
                for (int i = 0; i < TM; ++i)
#pragma unroll
                    for (int j = 0; j < 2; ++j)
                        acc[i][j] = fmaf(a_[i], b_[j], acc[i][j]);
            }
        }
        __syncthreads();
    }

    // ---- store (M always a multiple of BM for this problem) ----
#pragma unroll
    for (int i = 0; i < TM; ++i) {
        int gr = bm + row0 + i;
#pragma unroll
        for (int j = 0; j < TN; ++j) {
            int gc = bn + col0 + j;
            if (gc < N) {
                float v = acc[i][j];
                if (bias) v += bias[gc];
                if (MODE_C == 0) {
                    C[(size_t)gr * ldc + gc] = v;
                } else {
                    int l = gr / B_;
                    int b = gr % B_;
                    C[(size_t)b * (L_ * WV_) + (size_t)l * WV_ + gc] = v;
                }
            }
        }
    }
}

// z = xz(step) + hz; TF gate order i, j, f, o; forget bias 1.0
__global__ __launch_bounds__(256)
void lstm_cell(const float* __restrict__ xz,
               const float* __restrict__ hz,
               float* __restrict__ c,
               float* __restrict__ h,
               float* __restrict__ hs_out)
{
    int idx = blockIdx.x * 256 + threadIdx.x;
    if (idx >= B_ * H_) return;
    int b = idx >> 10;            // / H_
    int hh = idx & (H_ - 1);      // % H_
    size_t base = (size_t)b * (4 * H_) + hh;
    float zi = xz[base]           + hz[base];
    float zj = xz[base + H_]      + hz[base + H_];
    float zf = xz[base + 2 * H_]  + hz[base + 2 * H_];
    float zo = xz[base + 3 * H_]  + hz[base + 3 * H_];
    float cv = c[idx];
    float cn = cv * sigf(zf + 1.0f) + sigf(zi) * tanhf(zj);
    float hn = tanhf(cn) * sigf(zo);
    c[idx] = cn;
    h[idx] = hn;
    if (hs_out) hs_out[idx] = hn;
}

// dec_in[(l*B+b)*WV + v] = embeddings[caption[b*L + l], v]
__global__ __launch_bounds__(256)
void gather_emb(const int* __restrict__ cap,
                const float* __restrict__ emb,
                float* __restrict__ dec_in)
{
    int idx = blockIdx.x * 256 + threadIdx.x;
    if (idx >= L_ * B_ * WV_) return;
    int v = idx % WV_;
    int r = idx / WV_;
    int l = r / B_;
    int b = r % B_;
    dec_in[idx] = emb[(size_t)cap[b * L_ + l] * WV_ + v];
}

extern "C" void kernel_launch(void* const* d_in, const int* in_sizes, int n_in,
                              void* d_out, int out_size, void* d_ws, size_t ws_size,
                              hipStream_t stream)
{
    (void)in_sizes; (void)n_in; (void)out_size; (void)ws_size;
    const float* frames     = (const float*)d_in[0];
    const int*   caption    = (const int*)d_in[1];
    const float* embeddings = (const float*)d_in[2];
    const float* enc_kernel = (const float*)d_in[3];
    const float* enc_bias   = (const float*)d_in[4];
    const float* dec_kernel = (const float*)d_in[5];
    const float* dec_bias   = (const float*)d_in[6];
    const float* proj_W     = (const float*)d_in[7];
    const float* proj_b     = (const float*)d_in[8];
    float* out = (float*)d_out;

    float* ws     = (float*)d_ws;
    float* xz_enc = ws;                                  // [T*B, 4H]
    float* xz_dec = xz_enc + (size_t)T_ * B_ * 4 * H_;   // [L*B, 4H]
    float* hz     = xz_dec + (size_t)L_ * B_ * 4 * H_;   // [B, 4H]
    float* hbuf   = hz     + (size_t)B_ * 4 * H_;        // [B, H]
    float* cbuf   = hbuf   + (size_t)B_ * H_;            // [B, H]
    float* dec_in = cbuf   + (size_t)B_ * H_;            // [L*B, WV]
    float* hs     = dec_in + (size_t)L_ * B_ * WV_;      // [L*B, H]

    hipMemsetAsync(hbuf, 0, (size_t)B_ * H_ * sizeof(float), stream);
    hipMemsetAsync(cbuf, 0, (size_t)B_ * H_ * sizeof(float), stream);

    gather_emb<<<(L_ * B_ * WV_ + 255) / 256, 256, 0, stream>>>(caption, embeddings, dec_in);

    // encoder input projection (all timesteps at once): [T*B, F] @ Wx
    gemm_f32<64, 64, 4, 4, 1, 0><<<dim3(T_ * B_ / 64, 4 * H_ / 64), 256, 0, stream>>>(
        T_ * B_, 4 * H_, F_, frames, 0, enc_kernel, 4 * H_, enc_bias, xz_enc, 4 * H_);

    // decoder input projection: [L*B, WV] @ Wx_dec
    gemm_f32<64, 64, 4, 4, 0, 0><<<dim3(L_ * B_ / 64, 4 * H_ / 64), 256, 0, stream>>>(
        L_ * B_, 4 * H_, WV_, dec_in, WV_, dec_kernel, 4 * H_, dec_bias, xz_dec, 4 * H_);

    const float* WhE = enc_kernel + (size_t)F_ * 4 * H_;
    const float* WhD = dec_kernel + (size_t)WV_ * 4 * H_;

    for (int t = 0; t < T_; ++t) {
        gemm_f32<64, 32, 4, 2, 0, 0><<<dim3(B_ / 64, 4 * H_ / 32), 256, 0, stream>>>(
            B_, 4 * H_, H_, hbuf, H_, WhE, 4 * H_, nullptr, hz, 4 * H_);
        lstm_cell<<<(B_ * H_) / 256, 256, 0, stream>>>(
            xz_enc + (size_t)t * B_ * 4 * H_, hz, cbuf, hbuf, nullptr);
    }
    for (int l = 0; l < L_; ++l) {
        gemm_f32<64, 32, 4, 2, 0, 0><<<dim3(B_ / 64, 4 * H_ / 32), 256, 0, stream>>>(
            B_, 4 * H_, H_, hbuf, H_, WhD, 4 * H_, nullptr, hz, 4 * H_);
        lstm_cell<<<(B_ * H_) / 256, 256, 0, stream>>>(
            xz_dec + (size_t)l * B_ * 4 * H_, hz, cbuf, hbuf, hs + (size_t)l * B_ * H_);
    }

    // projection + transpose to [B, L, WV]
    gemm_f32<64, 64, 4, 4, 0, 1><<<dim3(L_ * B_ / 64, (WV_ + 63) / 64), 256, 0, stream>>>(
        L_ * B_, WV_, H_, hs, H_, proj_W, WV_, proj_b, out, WV_);
}

// Round 6
// 2500.225 us; speedup vs baseline: 1.8414x; 1.8414x over previous
//
#include <hip/hip_runtime.h>
#include <math.h>

#define B_ 128
#define T_ 32
#define F_ 2048
#define H_ 1024
#define L_ 20
#define WV_ 300
#define WVP_ 320   // dec input K padded to mult of 32
#define NPJ_ 384   // proj N padded to mult of 128

typedef unsigned short u16;
typedef unsigned int u32;
typedef __attribute__((ext_vector_type(8))) short bf16x8;  // 8 bf16 = 4 VGPRs
typedef __attribute__((ext_vector_type(4))) float f32x4;

__device__ __forceinline__ u16 f2bf(float x) {
    union { float f; u32 u; } v; v.f = x;
    return (u16)((v.u + 0x7FFFu + ((v.u >> 16) & 1u)) >> 16);  // RNE
}
__device__ __forceinline__ float bf2f(u16 x) {
    union { u32 u; float f; } v; v.u = ((u32)x) << 16; return v.f;
}
// exact 3-term split: x = hi + mid + lo + r, |r| <= 2^-27 |x|
__device__ __forceinline__ void split3(float x, u16& h, u16& m, u16& l) {
    h = f2bf(x);  float r1 = x - bf2f(h);   // exact (Sterbenz)
    m = f2bf(r1); float r2 = r1 - bf2f(m);  // exact
    l = f2bf(r2);
}
__device__ __forceinline__ float sigf(float x) { return 1.0f / (1.0f + expf(-x)); }

__device__ __forceinline__ void g2lds16(const void* g, void* l) {
    __builtin_amdgcn_global_load_lds((const __attribute__((address_space(1))) void*)g,
                                     (__attribute__((address_space(3))) void*)l, 16, 0, 0);
}

// MFMA fragment read (16 rows x 32 k) from a [X][32]-u16 LDS tile with
// 16B-chunk XOR swizzle: byte = r*64 + ((chunk ^ ((r>>1)&3))<<4).
__device__ __forceinline__ bf16x8 fragld(const u16* tile, int rbase, int lane) {
    int r = rbase + (lane & 15);
    int byte = r * 64 + ((((lane >> 4) ^ (r >> 1)) & 3) << 4);
    return *(const bf16x8*)((const char*)tile + byte);
}

// stage slot s (16B) of a [rows][32]-u16 tile; src points at tile's first row
__device__ __forceinline__ void stage_tile(const u16* src, int row_stride, int k0,
                                           u16* lds, int s) {
    int row = s >> 2;
    int ch = (s & 3) ^ ((row >> 1) & 3);   // inverse swizzle on the GLOBAL side
    g2lds16(src + (size_t)row * row_stride + k0 + ch * 8, lds + (size_t)s * 8);
}

// ---------- 6-pass split-bf16 TN GEMM: C = A @ Bt^T + bias (fp32-accurate) ----
// A, Bt each 3 bf16 planes (plane strides aps/bps). 128x128 tile, 4 waves.
// MODE_C: 0 = linear fp32 C[ldc]; 1 = proj scatter r=l*B+b -> out[b][l][col]
template<int MODE_C>
__global__ __launch_bounds__(256)
void gemm6_tn(int M, int N, int K, int Nreal,
              const u16* __restrict__ A, int lda, size_t aps,
              const u16* __restrict__ Bt, int ldb, size_t bps,
              const float* __restrict__ bias, float* __restrict__ C, int ldc)
{
    __shared__ u16 As[3][128 * 32];
    __shared__ u16 Bs[3][128 * 32];
    const int tid = threadIdx.x, lane = tid & 63, wid = tid >> 6;
    const int wr = wid >> 1, wc = wid & 1;
    const int bm = blockIdx.x * 128, bn = blockIdx.y * 128;

    f32x4 acc[4][4] = {};
    const u16* Ar = A + (size_t)bm * lda;
    const u16* Br = Bt + (size_t)bn * ldb;

    for (int k0 = 0; k0 < K; k0 += 32) {
#pragma unroll
        for (int p = 0; p < 3; ++p) {
            stage_tile(Ar + p * aps, lda, k0, (u16*)As[p], tid);
            stage_tile(Ar + p * aps, lda, k0, (u16*)As[p], tid + 256);
            stage_tile(Br + p * bps, ldb, k0, (u16*)Bs[p], tid);
            stage_tile(Br + p * bps, ldb, k0, (u16*)Bs[p], tid + 256);
        }
        __syncthreads();
        bf16x8 af[3][4];
#pragma unroll
        for (int p = 0; p < 3; ++p)
#pragma unroll
            for (int m = 0; m < 4; ++m) af[p][m] = fragld(As[p], wr * 64 + m * 16, lane);
        // pass order small->large; pairs: (a0,b2) (a1,b1)(a0,b1) (a2,b0)(a1,b0)(a0,b0)
        {
            bf16x8 bf[4];
#pragma unroll
            for (int n = 0; n < 4; ++n) bf[n] = fragld(Bs[2], wc * 64 + n * 16, lane);
#pragma unroll
            for (int m = 0; m < 4; ++m)
#pragma unroll
                for (int n = 0; n < 4; ++n)
                    acc[m][n] = __builtin_amdgcn_mfma_f32_16x16x32_bf16(af[0][m], bf[n], acc[m][n], 0, 0, 0);
        }
        {
            bf16x8 bf[4];
#pragma unroll
            for (int n = 0; n < 4; ++n) bf[n] = fragld(Bs[1], wc * 64 + n * 16, lane);
#pragma unroll
            for (int m = 0; m < 4; ++m)
#pragma unroll
                for (int n = 0; n < 4; ++n)
                    acc[m][n] = __builtin_amdgcn_mfma_f32_16x16x32_bf16(af[1][m], bf[n], acc[m][n], 0, 0, 0);
#pragma unroll
            for (int m = 0; m < 4; ++m)
#pragma unroll
                for (int n = 0; n < 4; ++n)
                    acc[m][n] = __builtin_amdgcn_mfma_f32_16x16x32_bf16(af[0][m], bf[n], acc[m][n], 0, 0, 0);
        }
        {
            bf16x8 bf[4];
#pragma unroll
            for (int n = 0; n < 4; ++n) bf[n] = fragld(Bs[0], wc * 64 + n * 16, lane);
#pragma unroll
            for (int m = 0; m < 4; ++m)
#pragma unroll
                for (int n = 0; n < 4; ++n)
                    acc[m][n] = __builtin_amdgcn_mfma_f32_16x16x32_bf16(af[2][m], bf[n], acc[m][n], 0, 0, 0);
#pragma unroll
            for (int m = 0; m < 4; ++m)
#pragma unroll
                for (int n = 0; n < 4; ++n)
                    acc[m][n] = __builtin_amdgcn_mfma_f32_16x16x32_bf16(af[1][m], bf[n], acc[m][n], 0, 0, 0);
#pragma unroll
            for (int m = 0; m < 4; ++m)
#pragma unroll
                for (int n = 0; n < 4; ++n)
                    acc[m][n] = __builtin_amdgcn_mfma_f32_16x16x32_bf16(af[0][m], bf[n], acc[m][n], 0, 0, 0);
        }
        __syncthreads();
    }

    // C/D layout: col = lane&15, row = (lane>>4)*4 + reg   [m89-verified]
    const int rq = (lane >> 4) << 2;
    const int cl = lane & 15;
#pragma unroll
    for (int m = 0; m < 4; ++m) {
        int grow = bm + wr * 64 + m * 16 + rq;
#pragma unroll
        for (int n = 0; n < 4; ++n) {
            int gcol = bn + wc * 64 + n * 16 + cl;
            if (gcol < Nreal) {
                float bv = bias ? bias[gcol] : 0.0f;
#pragma unroll
                for (int r = 0; r < 4; ++r) {
                    float v = acc[m][n][r] + bv;
                    int rr = grow + r;
                    if (MODE_C == 0) {
                        C[(size_t)rr * ldc + gcol] = v;
                    } else {
                        int l = rr >> 7, b = rr & 127;
                        C[((size_t)b * L_ + l) * WV_ + gcol] = v;
                    }
                }
            }
        }
    }
}

// ---------- fused recurrent step, 6-pass: z = h@Wh (4 gates) -> cell ----------
// grid 128: blk&1 = row half (64 rows), blk>>1 = 16-wide h-tile.
__global__ __launch_bounds__(256)
void lstm_step6(const u16* __restrict__ hp,   // 3p [128][1024] bf16
                const u16* __restrict__ WhT,  // 3p [4096][1024] bf16 (transposed)
                const float* __restrict__ xz, // [128][4096] fp32 (this step)
                float* __restrict__ c,        // [128][1024] fp32 (in-place)
                u16* __restrict__ hop,        // 3p [128][1024] out
                u16* __restrict__ hsp)        // 3p [*][1024] out (stride HSP), nullable
{
    const size_t HP = 128 * 1024, WHP = (size_t)4096 * 1024, HSP = (size_t)2560 * 1024;
    __shared__ u16 As[3][64 * 32];
    __shared__ u16 Bs[3][64 * 32];
    __shared__ float zs[64 * 68];
    const int tid = threadIdx.x, lane = tid & 63, w = tid >> 6;
    const int r0 = (blockIdx.x & 1) * 64;
    const int h0 = (blockIdx.x >> 1) * 16;

    f32x4 acc[4] = {};

    const int srow = tid >> 2;
    const int sch = (tid & 3) ^ ((srow >> 1) & 3);
    const u16* a0s = hp + (size_t)(r0 + srow) * 1024 + sch * 8;
    const int wrow = (srow >> 4) * 1024 + h0 + (srow & 15);   // gate*1024 + h0 + col
    const u16* b0s = WhT + (size_t)wrow * 1024 + sch * 8;

    for (int k0 = 0; k0 < 1024; k0 += 32) {
        g2lds16(a0s + k0,            &As[0][tid * 8]);
        g2lds16(a0s + HP + k0,       &As[1][tid * 8]);
        g2lds16(a0s + 2 * HP + k0,   &As[2][tid * 8]);
        g2lds16(b0s + k0,            &Bs[0][tid * 8]);
        g2lds16(b0s + WHP + k0,      &Bs[1][tid * 8]);
        g2lds16(b0s + 2 * WHP + k0,  &Bs[2][tid * 8]);
        __syncthreads();
        bf16x8 a0 = fragld(As[0], w * 16, lane);
        bf16x8 a1 = fragld(As[1], w * 16, lane);
        bf16x8 a2 = fragld(As[2], w * 16, lane);
        bf16x8 b0[4], b1[4], b2[4];
#pragma unroll
        for (int n = 0; n < 4; ++n) {
            b0[n] = fragld(Bs[0], n * 16, lane);
            b1[n] = fragld(Bs[1], n * 16, lane);
            b2[n] = fragld(Bs[2], n * 16, lane);
        }
        // small->large: (a0,b2) (a1,b1) (a0,b1) (a2,b0) (a1,b0) (a0,b0)
#pragma unroll
        for (int n = 0; n < 4; ++n) acc[n] = __builtin_amdgcn_mfma_f32_16x16x32_bf16(a0, b2[n], acc[n], 0, 0, 0);
#pragma unroll
        for (int n = 0; n < 4; ++n) acc[n] = __builtin_amdgcn_mfma_f32_16x16x32_bf16(a1, b1[n], acc[n], 0, 0, 0);
#pragma unroll
        for (int n = 0; n < 4; ++n) acc[n] = __builtin_amdgcn_mfma_f32_16x16x32_bf16(a0, b1[n], acc[n], 0, 0, 0);
#pragma unroll
        for (int n = 0; n < 4; ++n) acc[n] = __builtin_amdgcn_mfma_f32_16x16x32_bf16(a2, b0[n], acc[n], 0, 0, 0);
#pragma unroll
        for (int n = 0; n < 4; ++n) acc[n] = __builtin_amdgcn_mfma_f32_16x16x32_bf16(a1, b0[n], acc[n], 0, 0, 0);
#pragma unroll
        for (int n = 0; n < 4; ++n) acc[n] = __builtin_amdgcn_mfma_f32_16x16x32_bf16(a0, b0[n], acc[n], 0, 0, 0);
        __syncthreads();
    }

    {   // accs -> zs[64][68]
        int zr = w * 16 + ((lane >> 4) << 2);
        int zc = lane & 15;
#pragma unroll
        for (int n = 0; n < 4; ++n)
#pragma unroll
            for (int r = 0; r < 4; ++r)
                zs[(size_t)(zr + r) * 68 + n * 16 + zc] = acc[n][r];
    }
    __syncthreads();

    {   // cell: 64 rows x 16 h-cols, 4 elems/thread; all fp32
        union F4 { float4 v; float a[4]; };
        int row = tid >> 2;
        int hcb = (tid & 3) * 4;
        int b = r0 + row;
        int h = h0 + hcb;
        const float* xzr = xz + (size_t)b * 4096;
        F4 zi, zj, zf, zo, xi, xj, xf, xo, cv, cn;
        zi.v = *(const float4*)&zs[(size_t)row * 68 + 0  + hcb];
        zj.v = *(const float4*)&zs[(size_t)row * 68 + 16 + hcb];
        zf.v = *(const float4*)&zs[(size_t)row * 68 + 32 + hcb];
        zo.v = *(const float4*)&zs[(size_t)row * 68 + 48 + hcb];
        xi.v = *(const float4*)(xzr + h);
        xj.v = *(const float4*)(xzr + 1024 + h);
        xf.v = *(const float4*)(xzr + 2048 + h);
        xo.v = *(const float4*)(xzr + 3072 + h);
        cv.v = *(const float4*)(c + (size_t)b * 1024 + h);
        u16 ph[4], pm[4], pl[4];
#pragma unroll
        for (int q = 0; q < 4; ++q) {
            float i_ = zi.a[q] + xi.a[q];
            float j_ = zj.a[q] + xj.a[q];
            float f_ = zf.a[q] + xf.a[q];
            float o_ = zo.a[q] + xo.a[q];
            float cc = cv.a[q] * sigf(f_ + 1.0f) + sigf(i_) * tanhf(j_);
            cn.a[q] = cc;
            float hn = tanhf(cc) * sigf(o_);
            split3(hn, ph[q], pm[q], pl[q]);
        }
        *(float4*)(c + (size_t)b * 1024 + h) = cn.v;
        size_t o = (size_t)b * 1024 + h;
        uint2 vh = make_uint2((u32)ph[0] | ((u32)ph[1] << 16), (u32)ph[2] | ((u32)ph[3] << 16));
        uint2 vm = make_uint2((u32)pm[0] | ((u32)pm[1] << 16), (u32)pm[2] | ((u32)pm[3] << 16));
        uint2 vl = make_uint2((u32)pl[0] | ((u32)pl[1] << 16), (u32)pl[2] | ((u32)pl[3] << 16));
        *(uint2*)(hop + o) = vh;
        *(uint2*)(hop + HP + o) = vm;
        *(uint2*)(hop + 2 * HP + o) = vl;
        if (hsp) {
            *(uint2*)(hsp + o) = vh;
            *(uint2*)(hsp + HSP + o) = vm;
            *(uint2*)(hsp + 2 * HSP + o) = vl;
        }
    }
}

// ---------- conversion / split kernels ----------------------------------------
// out[n][k] (3 planes) = split3(in[in_row0+k][n]), zero-padded over grid range
__global__ __launch_bounds__(256)
void transpose_split(const float* __restrict__ in, int ldin, int in_row0,
                     int K_in, int N_in, u16* __restrict__ out, int ldout, size_t ps)
{
    __shared__ float tl[32][33];
    const int tid = threadIdx.x;
    const int k0 = blockIdx.x * 32, n0 = blockIdx.y * 32;
    const int cc = tid & 31, rr = tid >> 5;
#pragma unroll
    for (int p = 0; p < 4; ++p) {
        int r = rr + p * 8;
        int k = k0 + r, n = n0 + cc;
        tl[r][cc] = (k < K_in && n < N_in) ? in[(size_t)(in_row0 + k) * ldin + n] : 0.0f;
    }
    __syncthreads();
#pragma unroll
    for (int p = 0; p < 4; ++p) {
        int nr = rr + p * 8;
        u16 h, m, l; split3(tl[cc][nr], h, m, l);
        size_t o = (size_t)(n0 + nr) * ldout + k0 + cc;
        out[o] = h; out[o + ps] = m; out[o + 2 * ps] = l;
    }
}

// frames chunk: rows rr in [0,1024), t = t0 + rr/128, b = rr%128 -> 3 planes [1024][2048]
__global__ __launch_bounds__(256)
void split_frames(const float* __restrict__ fr, int t0, u16* __restrict__ out, size_t ps)
{
    int row = blockIdx.x;
    int t = t0 + (row >> 7), b = row & 127;
    const float* src = fr + ((size_t)b * T_ + t) * F_;
    int off = threadIdx.x * 8;
    float4 v0 = *(const float4*)(src + off);
    float4 v1 = *(const float4*)(src + off + 4);
    float x[8] = {v0.x, v0.y, v0.z, v0.w, v1.x, v1.y, v1.z, v1.w};
    u16 h[8], m[8], l[8];
#pragma unroll
    for (int q = 0; q < 8; ++q) split3(x[q], h[q], m[q], l[q]);
    size_t o = (size_t)row * F_ + off;
    uint4 vh = make_uint4((u32)h[0] | ((u32)h[1] << 16), (u32)h[2] | ((u32)h[3] << 16),
                          (u32)h[4] | ((u32)h[5] << 16), (u32)h[6] | ((u32)h[7] << 16));
    uint4 vm = make_uint4((u32)m[0] | ((u32)m[1] << 16), (u32)m[2] | ((u32)m[3] << 16),
                          (u32)m[4] | ((u32)m[5] << 16), (u32)m[6] | ((u32)m[7] << 16));
    uint4 vl = make_uint4((u32)l[0] | ((u32)l[1] << 16), (u32)l[2] | ((u32)l[3] << 16),
                          (u32)l[4] | ((u32)l[5] << 16), (u32)l[6] | ((u32)l[7] << 16));
    *(uint4*)(out + o) = vh;
    *(uint4*)(out + ps + o) = vm;
    *(uint4*)(out + 2 * ps + o) = vl;
}

// dec_in[(l*B+b)][v] (3 planes) = split3(emb[caption[b][l]][v]), pad v>=300
__global__ __launch_bounds__(256)
void gather_split(const int* __restrict__ cap, const float* __restrict__ emb,
                  u16* __restrict__ out, size_t ps)
{
    int idx = blockIdx.x * 256 + threadIdx.x;
    if (idx >= 2560 * WVP_) return;
    int v = idx % WVP_;
    int r = idx / WVP_;
    int l = r >> 7, b = r & 127;
    float val = (v < WV_) ? emb[(size_t)cap[b * L_ + l] * WV_ + v] : 0.0f;
    u16 h, m, ll; split3(val, h, m, ll);
    out[idx] = h; out[idx + ps] = m; out[idx + 2 * ps] = ll;
}

// ---------- host ----------------------------------------------------------------
// Workspace map (MiB), peak 117 (< 120 verified-good in round 2):
//  [0,16)    XZ fp32 slab (8 steps x 128 x 4096)
//  [16,40)   WhE 3p
//  [40,52)   ACH 3p (frames chunk)
//  [52,100)  WXE 3p  -> after encoder: WhD 3p [52,76) | WXD 3p [76,83.5)
//                        | DECIN 3p [83.5,88.2) | WP 3p [88.2,90.5)
//  [100,115) HS 3p
//  [115,117) HB0 3p | HB1 3p | CB fp32
extern "C" void kernel_launch(void* const* d_in, const int* in_sizes, int n_in,
                              void* d_out, int out_size, void* d_ws, size_t ws_size,
                              hipStream_t stream)
{
    (void)in_sizes; (void)n_in; (void)out_size; (void)ws_size;
    const float* frames     = (const float*)d_in[0];
    const int*   caption    = (const int*)d_in[1];
    const float* embeddings = (const float*)d_in[2];
    const float* enc_kernel = (const float*)d_in[3];
    const float* enc_bias   = (const float*)d_in[4];
    const float* dec_kernel = (const float*)d_in[5];
    const float* dec_bias   = (const float*)d_in[6];
    const float* proj_W     = (const float*)d_in[7];
    const float* proj_b     = (const float*)d_in[8];
    float* out = (float*)d_out;

    char* base = (char*)d_ws;
    const size_t M1 = 1 << 20;
    const size_t WHP = (size_t)4096 * 1024;   // Wh plane elems
    const size_t ACHP = (size_t)1024 * 2048;
    const size_t WXEP = (size_t)4096 * 2048;
    const size_t WXDP = (size_t)4096 * 320;
    const size_t DECP = (size_t)2560 * 320;
    const size_t WPP  = (size_t)384 * 1024;
    const size_t HSP  = (size_t)2560 * 1024;
    const size_t HBP  = (size_t)128 * 1024;

    float* XZ  = (float*)(base);
    u16* WhE   = (u16*)(base + 16 * M1);
    u16* ACH   = (u16*)(base + 40 * M1);
    u16* WXE   = (u16*)(base + 52 * M1);
    u16* WhD   = (u16*)(base + 52 * M1);                       // overlay (post-enc)
    u16* WXD   = (u16*)((char*)WhD + 3 * WHP * 2);
    u16* DECIN = (u16*)((char*)WXD + 3 * WXDP * 2);
    u16* WP    = (u16*)((char*)DECIN + 3 * DECP * 2);
    u16* HS    = (u16*)(base + 100 * M1);
    u16* HB0   = (u16*)(base + 115 * M1);
    u16* HB1   = (u16*)((char*)HB0 + 3 * HBP * 2);
    float* CB  = (float*)((char*)HB1 + 3 * HBP * 2);

    // ---- encoder weight prep ----
    transpose_split<<<dim3(64, 128), 256, 0, stream>>>(enc_kernel, 4096, 0, 2048, 4096, WXE, 2048, WXEP);
    transpose_split<<<dim3(32, 128), 256, 0, stream>>>(enc_kernel, 4096, 2048, 1024, 4096, WhE, 1024, WHP);
    hipMemsetAsync(CB, 0, HBP * 4, stream);
    hipMemsetAsync(HB0, 0, 3 * HBP * 2, stream);

    u16* hb[2] = { HB0, HB1 };
    int cur = 0;

    // ---- encoder: 4 chunks of 8 timesteps ----
    for (int ch = 0; ch < 4; ++ch) {
        split_frames<<<1024, 256, 0, stream>>>(frames, ch * 8, ACH, ACHP);
        gemm6_tn<0><<<dim3(8, 32), 256, 0, stream>>>(1024, 4096, 2048, 4096,
            ACH, 2048, ACHP, WXE, 2048, WXEP, enc_bias, XZ, 4096);
        for (int tt = 0; tt < 8; ++tt) {
            lstm_step6<<<128, 256, 0, stream>>>(hb[cur], WhE, XZ + (size_t)tt * 128 * 4096,
                CB, hb[cur ^ 1], (u16*)nullptr);
            cur ^= 1;
        }
    }

    // ---- decoder weight prep (overlays WXE region; encoder GEMMs are done) ----
    transpose_split<<<dim3(32, 128), 256, 0, stream>>>(dec_kernel, 4096, 300, 1024, 4096, WhD, 1024, WHP);
    transpose_split<<<dim3(10, 128), 256, 0, stream>>>(dec_kernel, 4096, 0, 300, 4096, WXD, 320, WXDP);
    transpose_split<<<dim3(32, 12), 256, 0, stream>>>(proj_W, 300, 0, 1024, 300, WP, 1024, WPP);
    gather_split<<<(2560 * WVP_ + 255) / 256, 256, 0, stream>>>(caption, embeddings, DECIN, DECP);

    // ---- decoder: chunks of 8,8,4 steps ----
    int l = 0;
    for (int ch = 0; ch < 3; ++ch) {
        int nl = (ch == 2) ? 4 : 8;
        gemm6_tn<0><<<dim3(nl, 32), 256, 0, stream>>>(nl * 128, 4096, 320, 4096,
            DECIN + (size_t)ch * 1024 * 320, 320, DECP, WXD, 320, WXDP, dec_bias, XZ, 4096);
        for (int q = 0; q < nl; ++q, ++l) {
            lstm_step6<<<128, 256, 0, stream>>>(hb[cur], WhD, XZ + (size_t)q * 128 * 4096,
                CB, hb[cur ^ 1], HS + (size_t)l * 128 * 1024);
            cur ^= 1;
        }
    }

    // ---- projection, scattered to [B][L][WV] ----
    gemm6_tn<1><<<dim3(20, 3), 256, 0, stream>>>(2560, NPJ_, 1024, 300,
        HS, 1024, HSP, WP, 1024, WPP, proj_b, out, 0);
}

// Round 8
// 2088.680 us; speedup vs baseline: 2.2042x; 1.1970x over previous
//
#include <hip/hip_runtime.h>
#include <math.h>

#define B_ 128
#define T_ 32
#define F_ 2048
#define H_ 1024
#define L_ 20
#define WV_ 300
#define WVP_ 320   // dec input K padded to mult of 32
#define NPJ_ 384   // proj N padded to mult of 128

typedef unsigned short u16;
typedef unsigned int u32;
typedef __attribute__((ext_vector_type(8))) short bf16x8;  // 8 bf16 = 4 VGPRs
typedef __attribute__((ext_vector_type(4))) float f32x4;

__device__ __forceinline__ u16 f2bf(float x) {
    union { float f; u32 u; } v; v.f = x;
    return (u16)((v.u + 0x7FFFu + ((v.u >> 16) & 1u)) >> 16);  // RNE
}
__device__ __forceinline__ float bf2f(u16 x) {
    union { u32 u; float f; } v; v.u = ((u32)x) << 16; return v.f;
}
// exact 3-term split: x = hi + mid + lo + r, |r| <= 2^-27 |x|
__device__ __forceinline__ void split3(float x, u16& h, u16& m, u16& l) {
    h = f2bf(x);  float r1 = x - bf2f(h);   // exact (Sterbenz)
    m = f2bf(r1); float r2 = r1 - bf2f(m);  // exact
    l = f2bf(r2);
}
__device__ __forceinline__ float sigf(float x) { return 1.0f / (1.0f + expf(-x)); }

__device__ __forceinline__ void g2lds16(const void* g, void* l) {
    __builtin_amdgcn_global_load_lds((const __attribute__((address_space(1))) void*)g,
                                     (__attribute__((address_space(3))) void*)l, 16, 0, 0);
}

// MFMA fragment read (16 rows x 32 k) from a [X][32]-u16 LDS tile with
// 16B-chunk XOR swizzle: byte = r*64 + ((chunk ^ ((r>>1)&3))<<4).
__device__ __forceinline__ bf16x8 fragld(const u16* tile, int rbase, int lane) {
    int r = rbase + (lane & 15);
    int byte = r * 64 + ((((lane >> 4) ^ (r >> 1)) & 3) << 4);
    return *(const bf16x8*)((const char*)tile + byte);
}

// stage slot s (16B) of a [rows][32]-u16 tile; src points at tile's first row
__device__ __forceinline__ void stage_tile(const u16* src, int row_stride, int k0,
                                           u16* lds, int s) {
    int row = s >> 2;
    int ch = (s & 3) ^ ((row >> 1) & 3);   // inverse swizzle on the GLOBAL side
    g2lds16(src + (size_t)row * row_stride + k0 + ch * 8, lds + (size_t)s * 8);
}

// ---------- 6-pass split-bf16 TN GEMM: C = A @ Bt^T + bias (fp32-accurate) ----
// A, Bt each 3 bf16 planes (plane strides aps/bps). 128x128 tile, 4 waves.
// MODE_C: 0 = linear fp32 C[ldc]; 1 = proj scatter r=l*B+b -> out[b][l][col]
template<int MODE_C>
__global__ __launch_bounds__(256)
void gemm6_tn(int M, int N, int K, int Nreal,
              const u16* __restrict__ A, int lda, size_t aps,
              const u16* __restrict__ Bt, int ldb, size_t bps,
              const float* __restrict__ bias, float* __restrict__ C, int ldc)
{
    __shared__ u16 As[3][128 * 32];
    __shared__ u16 Bs[3][128 * 32];
    const int tid = threadIdx.x, lane = tid & 63, wid = tid >> 6;
    const int wr = wid >> 1, wc = wid & 1;
    const int bm = blockIdx.x * 128, bn = blockIdx.y * 128;

    f32x4 acc[4][4] = {};
    const u16* Ar = A + (size_t)bm * lda;
    const u16* Br = Bt + (size_t)bn * ldb;

    for (int k0 = 0; k0 < K; k0 += 32) {
#pragma unroll
        for (int p = 0; p < 3; ++p) {
            stage_tile(Ar + p * aps, lda, k0, (u16*)As[p], tid);
            stage_tile(Ar + p * aps, lda, k0, (u16*)As[p], tid + 256);
            stage_tile(Br + p * bps, ldb, k0, (u16*)Bs[p], tid);
            stage_tile(Br + p * bps, ldb, k0, (u16*)Bs[p], tid + 256);
        }
        __syncthreads();
        bf16x8 af[3][4];
#pragma unroll
        for (int p = 0; p < 3; ++p)
#pragma unroll
            for (int m = 0; m < 4; ++m) af[p][m] = fragld(As[p], wr * 64 + m * 16, lane);
        // pass order small->large; pairs: (a0,b2) (a1,b1)(a0,b1) (a2,b0)(a1,b0)(a0,b0)
        {
            bf16x8 bf[4];
#pragma unroll
            for (int n = 0; n < 4; ++n) bf[n] = fragld(Bs[2], wc * 64 + n * 16, lane);
#pragma unroll
            for (int m = 0; m < 4; ++m)
#pragma unroll
                for (int n = 0; n < 4; ++n)
                    acc[m][n] = __builtin_amdgcn_mfma_f32_16x16x32_bf16(af[0][m], bf[n], acc[m][n], 0, 0, 0);
        }
        {
            bf16x8 bf[4];
#pragma unroll
            for (int n = 0; n < 4; ++n) bf[n] = fragld(Bs[1], wc * 64 + n * 16, lane);
#pragma unroll
            for (int m = 0; m < 4; ++m)
#pragma unroll
                for (int n = 0; n < 4; ++n)
                    acc[m][n] = __builtin_amdgcn_mfma_f32_16x16x32_bf16(af[1][m], bf[n], acc[m][n], 0, 0, 0);
#pragma unroll
            for (int m = 0; m < 4; ++m)
#pragma unroll
                for (int n = 0; n < 4; ++n)
                    acc[m][n] = __builtin_amdgcn_mfma_f32_16x16x32_bf16(af[0][m], bf[n], acc[m][n], 0, 0, 0);
        }
        {
            bf16x8 bf[4];
#pragma unroll
            for (int n = 0; n < 4; ++n) bf[n] = fragld(Bs[0], wc * 64 + n * 16, lane);
#pragma unroll
            for (int m = 0; m < 4; ++m)
#pragma unroll
                for (int n = 0; n < 4; ++n)
                    acc[m][n] = __builtin_amdgcn_mfma_f32_16x16x32_bf16(af[2][m], bf[n], acc[m][n], 0, 0, 0);
#pragma unroll
            for (int m = 0; m < 4; ++m)
#pragma unroll
                for (int n = 0; n < 4; ++n)
                    acc[m][n] = __builtin_amdgcn_mfma_f32_16x16x32_bf16(af[1][m], bf[n], acc[m][n], 0, 0, 0);
#pragma unroll
            for (int m = 0; m < 4; ++m)
#pragma unroll
                for (int n = 0; n < 4; ++n)
                    acc[m][n] = __builtin_amdgcn_mfma_f32_16x16x32_bf16(af[0][m], bf[n], acc[m][n], 0, 0, 0);
        }
        __syncthreads();
    }

    // C/D layout: col = lane&15, row = (lane>>4)*4 + reg   [m89-verified]
    const int rq = (lane >> 4) << 2;
    const int cl = lane & 15;
#pragma unroll
    for (int m = 0; m < 4; ++m) {
        int grow = bm + wr * 64 + m * 16 + rq;
#pragma unroll
        for (int n = 0; n < 4; ++n) {
            int gcol = bn + wc * 64 + n * 16 + cl;
            if (gcol < Nreal) {
                float bv = bias ? bias[gcol] : 0.0f;
#pragma unroll
                for (int r = 0; r < 4; ++r) {
                    float v = acc[m][n][r] + bv;
                    int rr = grow + r;
                    if (MODE_C == 0) {
                        C[(size_t)rr * ldc + gcol] = v;
                    } else {
                        int l = rr >> 7, b = rr & 127;
                        C[((size_t)b * L_ + l) * WV_ + gcol] = v;
                    }
                }
            }
        }
    }
}

// ---------- fused recurrent step, 6-pass, v2 ----------------------------------
// grid 256: blk&63 = 16-wide h-tile, blk>>6 = 32-row quarter.
// Wh-slice sharers are at blk distance 64 (== 0 mod 8) -> same XCD under
// round-robin dispatch -> Wh slice read once into that XCD's L2.
// 2-phase double-buffered staging: issue next k-tile's global_load_lds BEFORE
// computing current tile; the end-of-iter __syncthreads (drains vmcnt) lands
// after compute, hiding load latency.
// Staging layout per buffer (1152 16B slots, LDS-linear):
//   slots [0,384):   A planes p=0..2, each [32 rows][32 k]   (128 slots each)
//   slots [384,1152): B planes p=0..2, each [64 rows][32 k]  (256 slots each)
//   B row r = gate(r>>4) * 16-col-tile col (r&15)
__global__ __launch_bounds__(256)
void lstm_step6(const u16* __restrict__ hp,   // 3p [128][1024] bf16
                const u16* __restrict__ WhT,  // 3p [4096][1024] bf16 (transposed)
                const float* __restrict__ xz, // [128][4096] fp32 (this step)
                float* __restrict__ c,        // [128][1024] fp32 (in-place)
                u16* __restrict__ hop,        // 3p [128][1024] out
                u16* __restrict__ hsp)        // 3p [2560][1024] out, nullable
{
    const size_t HP = 128 * 1024, WHP = (size_t)4096 * 1024, HSP = (size_t)2560 * 1024;
    __shared__ u16 stg[2][9216];   // 2 x 1152 slots x 16B
    __shared__ float zs[32 * 68];
    const int tid = threadIdx.x, lane = tid & 63, w = tid >> 6;
    const int ht = blockIdx.x & 63, q = blockIdx.x >> 6;
    const int r0 = q * 32;
    const int h0 = ht * 16;

    f32x4 acc[2] = {};

    auto STAGE = [&](int bsel, int k0) {
        u16* dstb = &stg[bsel][0];
#pragma unroll
        for (int j = 0; j < 5; ++j) {
            int s = tid + j * 256;
            if (s < 1152) {
                u16* dst = dstb + s * 8;
                if (s < 384) {
                    int p = s >> 7, l = s & 127, row = l >> 2;
                    int ch = (l & 3) ^ ((row >> 1) & 3);
                    g2lds16(hp + (size_t)p * HP + (size_t)(r0 + row) * 1024 + k0 + ch * 8, dst);
                } else {
                    int t2 = s - 384;
                    int p = t2 >> 8, l = t2 & 255, row = l >> 2;
                    int ch = (l & 3) ^ ((row >> 1) & 3);
                    int wrow = (row >> 4) * 1024 + h0 + (row & 15);
                    g2lds16(WhT + (size_t)p * WHP + (size_t)wrow * 1024 + k0 + ch * 8, dst);
                }
            }
        }
    };

    STAGE(0, 0);
    __syncthreads();
    for (int t = 0; t < 32; ++t) {
        int pb = t & 1;
        if (t < 31) STAGE(pb ^ 1, (t + 1) * 32);   // prefetch next k-tile
        const u16* sb = stg[pb];
        bf16x8 a[3][2], bfr[3];
#pragma unroll
        for (int p = 0; p < 3; ++p) {
#pragma unroll
            for (int m = 0; m < 2; ++m) a[p][m] = fragld(sb + p * 1024, m * 16, lane);
            bfr[p] = fragld(sb + 3072 + p * 2048, w * 16, lane);
        }
        // small->large: (a0,b2) (a1,b1) (a0,b1) (a2,b0) (a1,b0) (a0,b0)
#pragma unroll
        for (int m = 0; m < 2; ++m) acc[m] = __builtin_amdgcn_mfma_f32_16x16x32_bf16(a[0][m], bfr[2], acc[m], 0, 0, 0);
#pragma unroll
        for (int m = 0; m < 2; ++m) acc[m] = __builtin_amdgcn_mfma_f32_16x16x32_bf16(a[1][m], bfr[1], acc[m], 0, 0, 0);
#pragma unroll
        for (int m = 0; m < 2; ++m) acc[m] = __builtin_amdgcn_mfma_f32_16x16x32_bf16(a[0][m], bfr[1], acc[m], 0, 0, 0);
#pragma unroll
        for (int m = 0; m < 2; ++m) acc[m] = __builtin_amdgcn_mfma_f32_16x16x32_bf16(a[2][m], bfr[0], acc[m], 0, 0, 0);
#pragma unroll
        for (int m = 0; m < 2; ++m) acc[m] = __builtin_amdgcn_mfma_f32_16x16x32_bf16(a[1][m], bfr[0], acc[m], 0, 0, 0);
#pragma unroll
        for (int m = 0; m < 2; ++m) acc[m] = __builtin_amdgcn_mfma_f32_16x16x32_bf16(a[0][m], bfr[0], acc[m], 0, 0, 0);
        __syncthreads();   // waits prefetch (vmcnt) + all waves done with sb
    }

    {   // accs -> zs[32][68]; C/D layout col=lane&15, row=(lane>>4)*4+reg
        int zr = (lane >> 4) << 2;
        int zc = lane & 15;
#pragma unroll
        for (int m = 0; m < 2; ++m)
#pragma unroll
            for (int r = 0; r < 4; ++r)
                zs[(m * 16 + zr + r) * 68 + w * 16 + zc] = acc[m][r];
    }
    __syncthreads();

    {   // cell: 32 rows x 16 h-cols, 2 elems/thread; all fp32
        int row = tid >> 3;
        int cp = (tid & 7) * 2;
        int b = r0 + row;
        int h = h0 + cp;
        const float* xzr = xz + (size_t)b * 4096;
        float2 zi = *(const float2*)&zs[row * 68 + 0  + cp];
        float2 zj = *(const float2*)&zs[row * 68 + 16 + cp];
        float2 zf = *(const float2*)&zs[row * 68 + 32 + cp];
        float2 zo = *(const float2*)&zs[row * 68 + 48 + cp];
        float2 xi = *(const float2*)(xzr + h);
        float2 xj = *(const float2*)(xzr + 1024 + h);
        float2 xf = *(const float2*)(xzr + 2048 + h);
        float2 xo = *(const float2*)(xzr + 3072 + h);
        float2 cv = *(const float2*)(c + (size_t)b * 1024 + h);
        float zia[2] = {zi.x, zi.y}, zja[2] = {zj.x, zj.y};
        float zfa[2] = {zf.x, zf.y}, zoa[2] = {zo.x, zo.y};
        float xia[2] = {xi.x, xi.y}, xja[2] = {xj.x, xj.y};
        float xfa[2] = {xf.x, xf.y}, xoa[2] = {xo.x, xo.y};
        float cva[2] = {cv.x, cv.y};
        float cn[2];
        u16 ph[2], pm[2], pl[2];
#pragma unroll
        for (int e = 0; e < 2; ++e) {
            float i_ = zia[e] + xia[e];
            float j_ = zja[e] + xja[e];
            float f_ = zfa[e] + xfa[e];
            float o_ = zoa[e] + xoa[e];
            float cc = cva[e] * sigf(f_ + 1.0f) + sigf(i_) * tanhf(j_);
            cn[e] = cc;
            float hn = tanhf(cc) * sigf(o_);
            split3(hn, ph[e], pm[e], pl[e]);
        }
        *(float2*)(c + (size_t)b * 1024 + h) = make_float2(cn[0], cn[1]);
        size_t o = (size_t)b * 1024 + h;
        u32 vh = (u32)ph[0] | ((u32)ph[1] << 16);
        u32 vm = (u32)pm[0] | ((u32)pm[1] << 16);
        u32 vl = (u32)pl[0] | ((u32)pl[1] << 16);
        *(u32*)(hop + o) = vh;
        *(u32*)(hop + HP + o) = vm;
        *(u32*)(hop + 2 * HP + o) = vl;
        if (hsp) {
            *(u32*)(hsp + o) = vh;
            *(u32*)(hsp + HSP + o) = vm;
            *(u32*)(hsp + 2 * HSP + o) = vl;
        }
    }
}

// ---------- conversion / split kernels ----------------------------------------
// out[n][k] (3 planes) = split3(in[in_row0+k][n]), zero-padded over grid range
__global__ __launch_bounds__(256)
void transpose_split(const float* __restrict__ in, int ldin, int in_row0,
                     int K_in, int N_in, u16* __restrict__ out, int ldout, size_t ps)
{
    __shared__ float tl[32][33];
    const int tid = threadIdx.x;
    const int k0 = blockIdx.x * 32, n0 = blockIdx.y * 32;
    const int cc = tid & 31, rr = tid >> 5;
#pragma unroll
    for (int p = 0; p < 4; ++p) {
        int r = rr + p * 8;
        int k = k0 + r, n = n0 + cc;
        tl[r][cc] = (k < K_in && n < N_in) ? in[(size_t)(in_row0 + k) * ldin + n] : 0.0f;
    }
    __syncthreads();
#pragma unroll
    for (int p = 0; p < 4; ++p) {
        int nr = rr + p * 8;
        u16 h, m, l; split3(tl[cc][nr], h, m, l);
        size_t o = (size_t)(n0 + nr) * ldout + k0 + cc;
        out[o] = h; out[o + ps] = m; out[o + 2 * ps] = l;
    }
}

// frames chunk: rows rr in [0,1024), t = t0 + rr/128, b = rr%128 -> 3 planes [1024][2048]
__global__ __launch_bounds__(256)
void split_frames(const float* __restrict__ fr, int t0, u16* __restrict__ out, size_t ps)
{
    int row = blockIdx.x;
    int t = t0 + (row >> 7), b = row & 127;
    const float* src = fr + ((size_t)b * T_ + t) * F_;
    int off = threadIdx.x * 8;
    float4 v0 = *(const float4*)(src + off);
    float4 v1 = *(const float4*)(src + off + 4);
    float x[8] = {v0.x, v0.y, v0.z, v0.w, v1.x, v1.y, v1.z, v1.w};
    u16 h[8], m[8], l[8];
#pragma unroll
    for (int q = 0; q < 8; ++q) split3(x[q], h[q], m[q], l[q]);
    size_t o = (size_t)row * F_ + off;
    uint4 vh = make_uint4((u32)h[0] | ((u32)h[1] << 16), (u32)h[2] | ((u32)h[3] << 16),
                          (u32)h[4] | ((u32)h[5] << 16), (u32)h[6] | ((u32)h[7] << 16));
    uint4 vm = make_uint4((u32)m[0] | ((u32)m[1] << 16), (u32)m[2] | ((u32)m[3] << 16),
                          (u32)m[4] | ((u32)m[5] << 16), (u32)m[6] | ((u32)m[7] << 16));
    uint4 vl = make_uint4((u32)l[0] | ((u32)l[1] << 16), (u32)l[2] | ((u32)l[3] << 16),
                          (u32)l[4] | ((u32)l[5] << 16), (u32)l[6] | ((u32)l[7] << 16));
    *(uint4*)(out + o) = vh;
    *(uint4*)(out + ps + o) = vm;
    *(uint4*)(out + 2 * ps + o) = vl;
}

// dec_in[(l*B+b)][v] (3 planes) = split3(emb[caption[b][l]][v]), pad v>=300
__global__ __launch_bounds__(256)
void gather_split(const int* __restrict__ cap, const float* __restrict__ emb,
                  u16* __restrict__ out, size_t ps)
{
    int idx = blockIdx.x * 256 + threadIdx.x;
    if (idx >= 2560 * WVP_) return;
    int v = idx % WVP_;
    int r = idx / WVP_;
    int l = r >> 7, b = r & 127;
    float val = (v < WV_) ? emb[(size_t)cap[b * L_ + l] * WV_ + v] : 0.0f;
    u16 h, m, ll; split3(val, h, m, ll);
    out[idx] = h; out[idx + ps] = m; out[idx + 2 * ps] = ll;
}

// ---------- host ----------------------------------------------------------------
// Workspace map (MiB), peak 117 (< 120 verified-good in round 2):
//  [0,16)    XZ fp32 slab (8 steps x 128 x 4096)
//  [16,40)   WhE 3p
//  [40,52)   ACH 3p (frames chunk)
//  [52,100)  WXE 3p  -> after encoder: WhD 3p [52,76) | WXD 3p [76,83.5)
//                        | DECIN 3p [83.5,88.2) | WP 3p [88.2,90.5)
//  [100,115) HS 3p
//  [115,117) HB0 3p | HB1 3p | CB fp32
extern "C" void kernel_launch(void* const* d_in, const int* in_sizes, int n_in,
                              void* d_out, int out_size, void* d_ws, size_t ws_size,
                              hipStream_t stream)
{
    (void)in_sizes; (void)n_in; (void)out_size; (void)ws_size;
    const float* frames     = (const float*)d_in[0];
    const int*   caption    = (const int*)d_in[1];
    const float* embeddings = (const float*)d_in[2];
    const float* enc_kernel = (const float*)d_in[3];
    const float* enc_bias   = (const float*)d_in[4];
    const float* dec_kernel = (const float*)d_in[5];
    const float* dec_bias   = (const float*)d_in[6];
    const float* proj_W     = (const float*)d_in[7];
    const float* proj_b     = (const float*)d_in[8];
    float* out = (float*)d_out;

    char* base = (char*)d_ws;
    const size_t M1 = 1 << 20;
    const size_t WHP = (size_t)4096 * 1024;   // Wh plane elems
    const size_t ACHP = (size_t)1024 * 2048;
    const size_t WXEP = (size_t)4096 * 2048;
    const size_t WXDP = (size_t)4096 * 320;
    const size_t DECP = (size_t)2560 * 320;
    const size_t WPP  = (size_t)384 * 1024;
    const size_t HSP  = (size_t)2560 * 1024;
    const size_t HBP  = (size_t)128 * 1024;

    float* XZ  = (float*)(base);
    u16* WhE   = (u16*)(base + 16 * M1);
    u16* ACH   = (u16*)(base + 40 * M1);
    u16* WXE   = (u16*)(base + 52 * M1);
    u16* WhD   = (u16*)(base + 52 * M1);                       // overlay (post-enc)
    u16* WXD   = (u16*)((char*)WhD + 3 * WHP * 2);
    u16* DECIN = (u16*)((char*)WXD + 3 * WXDP * 2);
    u16* WP    = (u16*)((char*)DECIN + 3 * DECP * 2);
    u16* HS    = (u16*)(base + 100 * M1);
    u16* HB0   = (u16*)(base + 115 * M1);
    u16* HB1   = (u16*)((char*)HB0 + 3 * HBP * 2);
    float* CB  = (float*)((char*)HB1 + 3 * HBP * 2);

    // ---- encoder weight prep ----
    transpose_split<<<dim3(64, 128), 256, 0, stream>>>(enc_kernel, 4096, 0, 2048, 4096, WXE, 2048, WXEP);
    transpose_split<<<dim3(32, 128), 256, 0, stream>>>(enc_kernel, 4096, 2048, 1024, 4096, WhE, 1024, WHP);
    hipMemsetAsync(CB, 0, HBP * 4, stream);
    hipMemsetAsync(HB0, 0, 3 * HBP * 2, stream);

    u16* hb[2] = { HB0, HB1 };
    int cur = 0;

    // ---- encoder: 4 chunks of 8 timesteps ----
    for (int ch = 0; ch < 4; ++ch) {
        split_frames<<<1024, 256, 0, stream>>>(frames, ch * 8, ACH, ACHP);
        gemm6_tn<0><<<dim3(8, 32), 256, 0, stream>>>(1024, 4096, 2048, 4096,
            ACH, 2048, ACHP, WXE, 2048, WXEP, enc_bias, XZ, 4096);
        for (int tt = 0; tt < 8; ++tt) {
            lstm_step6<<<256, 256, 0, stream>>>(hb[cur], WhE, XZ + (size_t)tt * 128 * 4096,
                CB, hb[cur ^ 1], (u16*)nullptr);
            cur ^= 1;
        }
    }

    // ---- decoder weight prep (overlays WXE region; encoder GEMMs are done) ----
    transpose_split<<<dim3(32, 128), 256, 0, stream>>>(dec_kernel, 4096, 300, 1024, 4096, WhD, 1024, WHP);
    transpose_split<<<dim3(10, 128), 256, 0, stream>>>(dec_kernel, 4096, 0, 300, 4096, WXD, 320, WXDP);
    transpose_split<<<dim3(32, 12), 256, 0, stream>>>(proj_W, 300, 0, 1024, 300, WP, 1024, WPP);
    gather_split<<<(2560 * WVP_ + 255) / 256, 256, 0, stream>>>(caption, embeddings, DECIN, DECP);

    // ---- decoder: chunks of 8,8,4 steps ----
    int l = 0;
    for (int ch = 0; ch < 3; ++ch) {
        int nl = (ch == 2) ? 4 : 8;
        gemm6_tn<0><<<dim3(nl, 32), 256, 0, stream>>>(nl * 128, 4096, 320, 4096,
            DECIN + (size_t)ch * 1024 * 320, 320, DECP, WXD, 320, WXDP, dec_bias, XZ, 4096);
        for (int q = 0; q < nl; ++q, ++l) {
            lstm_step6<<<256, 256, 0, stream>>>(hb[cur], WhD, XZ + (size_t)q * 128 * 4096,
                CB, hb[cur ^ 1], HS + (size_t)l * 128 * 1024);
            cur ^= 1;
        }
    }

    // ---- projection, scattered to [B][L][WV] ----
    gemm6_tn<1><<<dim3(20, 3), 256, 0, stream>>>(2560, NPJ_, 1024, 300,
        HS, 1024, HSP, WP, 1024, WPP, proj_b, out, 0);
}

// Round 9
// 1787.844 us; speedup vs baseline: 2.5751x; 1.1683x over previous
//
#include <hip/hip_runtime.h>
#include <math.h>

#define B_ 128
#define T_ 32
#define F_ 2048
#define H_ 1024
#define L_ 20
#define WV_ 300
#define WVP_ 320   // dec input K padded to mult of 32
#define NPJ_ 384   // proj N padded to mult of 128

typedef unsigned short u16;
typedef unsigned int u32;
typedef __attribute__((ext_vector_type(8))) short bf16x8;  // 8 bf16 = 4 VGPRs
typedef __attribute__((ext_vector_type(4))) float f32x4;

__device__ __forceinline__ u16 f2bf(float x) {
    union { float f; u32 u; } v; v.f = x;
    return (u16)((v.u + 0x7FFFu + ((v.u >> 16) & 1u)) >> 16);  // RNE
}
__device__ __forceinline__ float bf2f(u16 x) {
    union { u32 u; float f; } v; v.u = ((u32)x) << 16; return v.f;
}
// exact 3-term split: x = hi + mid + lo + r, |r| <= 2^-27 |x|
__device__ __forceinline__ void split3(float x, u16& h, u16& m, u16& l) {
    h = f2bf(x);  float r1 = x - bf2f(h);   // exact (Sterbenz)
    m = f2bf(r1); float r2 = r1 - bf2f(m);  // exact
    l = f2bf(r2);
}
__device__ __forceinline__ float sigf(float x) { return 1.0f / (1.0f + expf(-x)); }

__device__ __forceinline__ void g2lds16(const void* g, void* l) {
    __builtin_amdgcn_global_load_lds((const __attribute__((address_space(1))) void*)g,
                                     (__attribute__((address_space(3))) void*)l, 16, 0, 0);
}

// MFMA fragment read (16 rows x 32 k) from a [X][32]-u16 LDS tile with
// 16B-chunk XOR swizzle: byte = r*64 + ((chunk ^ ((r>>1)&3))<<4).
__device__ __forceinline__ bf16x8 fragld(const u16* tile, int rbase, int lane) {
    int r = rbase + (lane & 15);
    int byte = r * 64 + ((((lane >> 4) ^ (r >> 1)) & 3) << 4);
    return *(const bf16x8*)((const char*)tile + byte);
}

// stage slot s (16B) of a [rows][32]-u16 tile; src points at tile's first row
__device__ __forceinline__ void stage_tile(const u16* src, int row_stride, int k0,
                                           u16* lds, int s) {
    int row = s >> 2;
    int ch = (s & 3) ^ ((row >> 1) & 3);   // inverse swizzle on the GLOBAL side
    g2lds16(src + (size_t)row * row_stride + k0 + ch * 8, lds + (size_t)s * 8);
}

// ---------- 6-pass split-bf16 TN GEMM: C = A @ Bt^T + bias (fp32-accurate) ----
// A, Bt each 3 bf16 planes (plane strides aps/bps). 128x128 tile, 4 waves.
// 1-D grid; nb = bid % NB, mb = bid / NB. For NB mult of 8 this puts all
// M-blocks sharing a B-tile on the SAME XCD (bid % 8 == nb % 8) -> B fetched
// once per chip instead of once per XCD.
// Double-buffered LDS: prefetch k-tile t+1 before computing tile t; the single
// end-of-iter __syncthreads (drains vmcnt) lands after the 48 MFMAs.
// MODE_C: 0 = linear fp32 C[ldc]; 1 = proj scatter r=l*B+b -> out[b][l][col]
template<int MODE_C>
__global__ __launch_bounds__(256)
void gemm6_tn(int M, int N, int K, int Nreal, int NB,
              const u16* __restrict__ A, int lda, size_t aps,
              const u16* __restrict__ Bt, int ldb, size_t bps,
              const float* __restrict__ bias, float* __restrict__ C, int ldc)
{
    __shared__ u16 As[2][3][128 * 32];
    __shared__ u16 Bs[2][3][128 * 32];
    const int tid = threadIdx.x, lane = tid & 63, wid = tid >> 6;
    const int wr = wid >> 1, wc = wid & 1;
    const int bid = blockIdx.x;
    const int bm = (bid / NB) * 128, bn = (bid % NB) * 128;

    f32x4 acc[4][4] = {};
    const u16* Ar = A + (size_t)bm * lda;
    const u16* Br = Bt + (size_t)bn * ldb;

    auto STAGE = [&](int bsel, int k0) {
#pragma unroll
        for (int p = 0; p < 3; ++p) {
            stage_tile(Ar + p * aps, lda, k0, (u16*)As[bsel][p], tid);
            stage_tile(Ar + p * aps, lda, k0, (u16*)As[bsel][p], tid + 256);
            stage_tile(Br + p * bps, ldb, k0, (u16*)Bs[bsel][p], tid);
            stage_tile(Br + p * bps, ldb, k0, (u16*)Bs[bsel][p], tid + 256);
        }
    };

    const int KT = K >> 5;
    STAGE(0, 0);
    __syncthreads();
    for (int kt = 0; kt < KT; ++kt) {
        int pb = kt & 1;
        if (kt + 1 < KT) STAGE(pb ^ 1, (kt + 1) << 5);   // prefetch next k-tile
        bf16x8 af[3][4];
#pragma unroll
        for (int p = 0; p < 3; ++p)
#pragma unroll
            for (int m = 0; m < 4; ++m) af[p][m] = fragld(As[pb][p], wr * 64 + m * 16, lane);
        // pass order small->large; pairs: (a0,b2) (a1,b1)(a0,b1) (a2,b0)(a1,b0)(a0,b0)
        {
            bf16x8 bf[4];
#pragma unroll
            for (int n = 0; n < 4; ++n) bf[n] = fragld(Bs[pb][2], wc * 64 + n * 16, lane);
#pragma unroll
            for (int m = 0; m < 4; ++m)
#pragma unroll
                for (int n = 0; n < 4; ++n)
                    acc[m][n] = __builtin_amdgcn_mfma_f32_16x16x32_bf16(af[0][m], bf[n], acc[m][n], 0, 0, 0);
        }
        {
            bf16x8 bf[4];
#pragma unroll
            for (int n = 0; n < 4; ++n) bf[n] = fragld(Bs[pb][1], wc * 64 + n * 16, lane);
#pragma unroll
            for (int m = 0; m < 4; ++m)
#pragma unroll
                for (int n = 0; n < 4; ++n)
                    acc[m][n] = __builtin_amdgcn_mfma_f32_16x16x32_bf16(af[1][m], bf[n], acc[m][n], 0, 0, 0);
#pragma unroll
            for (int m = 0; m < 4; ++m)
#pragma unroll
                for (int n = 0; n < 4; ++n)
                    acc[m][n] = __builtin_amdgcn_mfma_f32_16x16x32_bf16(af[0][m], bf[n], acc[m][n], 0, 0, 0);
        }
        {
            bf16x8 bf[4];
#pragma unroll
            for (int n = 0; n < 4; ++n) bf[n] = fragld(Bs[pb][0], wc * 64 + n * 16, lane);
#pragma unroll
            for (int m = 0; m < 4; ++m)
#pragma unroll
                for (int n = 0; n < 4; ++n)
                    acc[m][n] = __builtin_amdgcn_mfma_f32_16x16x32_bf16(af[2][m], bf[n], acc[m][n], 0, 0, 0);
#pragma unroll
            for (int m = 0; m < 4; ++m)
#pragma unroll
                for (int n = 0; n < 4; ++n)
                    acc[m][n] = __builtin_amdgcn_mfma_f32_16x16x32_bf16(af[1][m], bf[n], acc[m][n], 0, 0, 0);
#pragma unroll
            for (int m = 0; m < 4; ++m)
#pragma unroll
                for (int n = 0; n < 4; ++n)
                    acc[m][n] = __builtin_amdgcn_mfma_f32_16x16x32_bf16(af[0][m], bf[n], acc[m][n], 0, 0, 0);
        }
        __syncthreads();   // waits prefetch (vmcnt) + all waves done with buffer pb
    }

    // C/D layout: col = lane&15, row = (lane>>4)*4 + reg   [m89-verified]
    const int rq = (lane >> 4) << 2;
    const int cl = lane & 15;
#pragma unroll
    for (int m = 0; m < 4; ++m) {
        int grow = bm + wr * 64 + m * 16 + rq;
#pragma unroll
        for (int n = 0; n < 4; ++n) {
            int gcol = bn + wc * 64 + n * 16 + cl;
            if (gcol < Nreal) {
                float bv = bias ? bias[gcol] : 0.0f;
#pragma unroll
                for (int r = 0; r < 4; ++r) {
                    float v = acc[m][n][r] + bv;
                    int rr = grow + r;
                    if (MODE_C == 0) {
                        C[(size_t)rr * ldc + gcol] = v;
                    } else {
                        int l = rr >> 7, b = rr & 127;
                        C[((size_t)b * L_ + l) * WV_ + gcol] = v;
                    }
                }
            }
        }
    }
}

// ---------- fused recurrent step, 6-pass, v3 (BK=64) ---------------------------
// grid 256: blk&63 = 16-wide h-tile, blk>>6 = 32-row quarter.
// Wh-slice sharers are at blk distance 64 (== 0 mod 8) -> same XCD.
// BK=64: each buffer holds TWO 32-k sub-tiles (identical per-sub-tile layout to
// v2), computed in ascending k order -> bitwise-identical arithmetic, but only
// 16 barrier drains instead of 32.
// Per-sub-tile layout (1152 16B slots): A planes p=0..2 [32r][32k] (128 slots
// each), then B planes p=0..2 [64r][32k] (256 slots each).
__global__ __launch_bounds__(256)
void lstm_step6(const u16* __restrict__ hp,   // 3p [128][1024] bf16
                const u16* __restrict__ WhT,  // 3p [4096][1024] bf16 (transposed)
                const float* __restrict__ xz, // [128][4096] fp32 (this step)
                float* __restrict__ c,        // [128][1024] fp32 (in-place)
                u16* __restrict__ hop,        // 3p [128][1024] out
                u16* __restrict__ hsp)        // 3p [2560][1024] out, nullable
{
    const size_t HP = 128 * 1024, WHP = (size_t)4096 * 1024, HSP = (size_t)2560 * 1024;
    __shared__ u16 stg[2][18432];  // 2 buf x 2 subtiles x 1152 slots x 16B
    __shared__ float zs[32 * 68];
    const int tid = threadIdx.x, lane = tid & 63, w = tid >> 6;
    const int ht = blockIdx.x & 63, q = blockIdx.x >> 6;
    const int r0 = q * 32;
    const int h0 = ht * 16;

    f32x4 acc[2] = {};

    auto STAGE = [&](int bsel, int k0) {   // stages 64 k (2 sub-tiles)
        u16* dstb = &stg[bsel][0];
#pragma unroll
        for (int j = 0; j < 9; ++j) {
            int s = tid + j * 256;          // s in [0, 2304)
            int sub = s / 1152;
            int s2 = s - sub * 1152;
            int kk = k0 + sub * 32;
            u16* dst = dstb + s * 8;
            if (s2 < 384) {
                int p = s2 >> 7, l = s2 & 127, row = l >> 2;
                int ch = (l & 3) ^ ((row >> 1) & 3);
                g2lds16(hp + (size_t)p * HP + (size_t)(r0 + row) * 1024 + kk + ch * 8, dst);
            } else {
                int t2 = s2 - 384;
                int p = t2 >> 8, l = t2 & 255, row = l >> 2;
                int ch = (l & 3) ^ ((row >> 1) & 3);
                int wrow = (row >> 4) * 1024 + h0 + (row & 15);
                g2lds16(WhT + (size_t)p * WHP + (size_t)wrow * 1024 + kk + ch * 8, dst);
            }
        }
    };

    STAGE(0, 0);
    __syncthreads();
    for (int t = 0; t < 16; ++t) {
        int pb = t & 1;
        if (t < 15) STAGE(pb ^ 1, (t + 1) * 64);   // prefetch next 64-k tile
#pragma unroll
        for (int sub = 0; sub < 2; ++sub) {
            const u16* sb = &stg[pb][sub * 9216];
            bf16x8 a[3][2], bfr[3];
#pragma unroll
            for (int p = 0; p < 3; ++p) {
#pragma unroll
                for (int m = 0; m < 2; ++m) a[p][m] = fragld(sb + p * 1024, m * 16, lane);
                bfr[p] = fragld(sb + 3072 + p * 2048, w * 16, lane);
            }
            // small->large: (a0,b2) (a1,b1) (a0,b1) (a2,b0) (a1,b0) (a0,b0)
#pragma unroll
            for (int m = 0; m < 2; ++m) acc[m] = __builtin_amdgcn_mfma_f32_16x16x32_bf16(a[0][m], bfr[2], acc[m], 0, 0, 0);
#pragma unroll
            for (int m = 0; m < 2; ++m) acc[m] = __builtin_amdgcn_mfma_f32_16x16x32_bf16(a[1][m], bfr[1], acc[m], 0, 0, 0);
#pragma unroll
            for (int m = 0; m < 2; ++m) acc[m] = __builtin_amdgcn_mfma_f32_16x16x32_bf16(a[0][m], bfr[1], acc[m], 0, 0, 0);
#pragma unroll
            for (int m = 0; m < 2; ++m) acc[m] = __builtin_amdgcn_mfma_f32_16x16x32_bf16(a[2][m], bfr[0], acc[m], 0, 0, 0);
#pragma unroll
            for (int m = 0; m < 2; ++m) acc[m] = __builtin_amdgcn_mfma_f32_16x16x32_bf16(a[1][m], bfr[0], acc[m], 0, 0, 0);
#pragma unroll
            for (int m = 0; m < 2; ++m) acc[m] = __builtin_amdgcn_mfma_f32_16x16x32_bf16(a[0][m], bfr[0], acc[m], 0, 0, 0);
        }
        __syncthreads();   // waits prefetch (vmcnt) + all waves done with buffer pb
    }

    {   // accs -> zs[32][68]; C/D layout col=lane&15, row=(lane>>4)*4+reg
        int zr = (lane >> 4) << 2;
        int zc = lane & 15;
#pragma unroll
        for (int m = 0; m < 2; ++m)
#pragma unroll
            for (int r = 0; r < 4; ++r)
                zs[(m * 16 + zr + r) * 68 + w * 16 + zc] = acc[m][r];
    }
    __syncthreads();

    {   // cell: 32 rows x 16 h-cols, 2 elems/thread; all fp32
        int row = tid >> 3;
        int cp = (tid & 7) * 2;
        int b = r0 + row;
        int h = h0 + cp;
        const float* xzr = xz + (size_t)b * 4096;
        float2 zi = *(const float2*)&zs[row * 68 + 0  + cp];
        float2 zj = *(const float2*)&zs[row * 68 + 16 + cp];
        float2 zf = *(const float2*)&zs[row * 68 + 32 + cp];
        float2 zo = *(const float2*)&zs[row * 68 + 48 + cp];
        float2 xi = *(const float2*)(xzr + h);
        float2 xj = *(const float2*)(xzr + 1024 + h);
        float2 xf = *(const float2*)(xzr + 2048 + h);
        float2 xo = *(const float2*)(xzr + 3072 + h);
        float2 cv = *(const float2*)(c + (size_t)b * 1024 + h);
        float zia[2] = {zi.x, zi.y}, zja[2] = {zj.x, zj.y};
        float zfa[2] = {zf.x, zf.y}, zoa[2] = {zo.x, zo.y};
        float xia[2] = {xi.x, xi.y}, xja[2] = {xj.x, xj.y};
        float xfa[2] = {xf.x, xf.y}, xoa[2] = {xo.x, xo.y};
        float cva[2] = {cv.x, cv.y};
        float cn[2];
        u16 ph[2], pm[2], pl[2];
#pragma unroll
        for (int e = 0; e < 2; ++e) {
            float i_ = zia[e] + xia[e];
            float j_ = zja[e] + xja[e];
            float f_ = zfa[e] + xfa[e];
            float o_ = zoa[e] + xoa[e];
            float cc = cva[e] * sigf(f_ + 1.0f) + sigf(i_) * tanhf(j_);
            cn[e] = cc;
            float hn = tanhf(cc) * sigf(o_);
            split3(hn, ph[e], pm[e], pl[e]);
        }
        *(float2*)(c + (size_t)b * 1024 + h) = make_float2(cn[0], cn[1]);
        size_t o = (size_t)b * 1024 + h;
        u32 vh = (u32)ph[0] | ((u32)ph[1] << 16);
        u32 vm = (u32)pm[0] | ((u32)pm[1] << 16);
        u32 vl = (u32)pl[0] | ((u32)pl[1] << 16);
        *(u32*)(hop + o) = vh;
        *(u32*)(hop + HP + o) = vm;
        *(u32*)(hop + 2 * HP + o) = vl;
        if (hsp) {
            *(u32*)(hsp + o) = vh;
            *(u32*)(hsp + HSP + o) = vm;
            *(u32*)(hsp + 2 * HSP + o) = vl;
        }
    }
}

// ---------- conversion / split kernels ----------------------------------------
// out[n][k] (3 planes) = split3(in[in_row0+k][n]), zero-padded over grid range
__global__ __launch_bounds__(256)
void transpose_split(const float* __restrict__ in, int ldin, int in_row0,
                     int K_in, int N_in, u16* __restrict__ out, int ldout, size_t ps)
{
    __shared__ float tl[32][33];
    const int tid = threadIdx.x;
    const int k0 = blockIdx.x * 32, n0 = blockIdx.y * 32;
    const int cc = tid & 31, rr = tid >> 5;
#pragma unroll
    for (int p = 0; p < 4; ++p) {
        int r = rr + p * 8;
        int k = k0 + r, n = n0 + cc;
        tl[r][cc] = (k < K_in && n < N_in) ? in[(size_t)(in_row0 + k) * ldin + n] : 0.0f;
    }
    __syncthreads();
#pragma unroll
    for (int p = 0; p < 4; ++p) {
        int nr = rr + p * 8;
        u16 h, m, l; split3(tl[cc][nr], h, m, l);
        size_t o = (size_t)(n0 + nr) * ldout + k0 + cc;
        out[o] = h; out[o + ps] = m; out[o + 2 * ps] = l;
    }
}

// frames chunk: rows rr in [0,1024), t = t0 + rr/128, b = rr%128 -> 3 planes [1024][2048]
__global__ __launch_bounds__(256)
void split_frames(const float* __restrict__ fr, int t0, u16* __restrict__ out, size_t ps)
{
    int row = blockIdx.x;
    int t = t0 + (row >> 7), b = row & 127;
    const float* src = fr + ((size_t)b * T_ + t) * F_;
    int off = threadIdx.x * 8;
    float4 v0 = *(const float4*)(src + off);
    float4 v1 = *(const float4*)(src + off + 4);
    float x[8] = {v0.x, v0.y, v0.z, v0.w, v1.x, v1.y, v1.z, v1.w};
    u16 h[8], m[8], l[8];
#pragma unroll
    for (int q = 0; q < 8; ++q) split3(x[q], h[q], m[q], l[q]);
    size_t o = (size_t)row * F_ + off;
    uint4 vh = make_uint4((u32)h[0] | ((u32)h[1] << 16), (u32)h[2] | ((u32)h[3] << 16),
                          (u32)h[4] | ((u32)h[5] << 16), (u32)h[6] | ((u32)h[7] << 16));
    uint4 vm = make_uint4((u32)m[0] | ((u32)m[1] << 16), (u32)m[2] | ((u32)m[3] << 16),
                          (u32)m[4] | ((u32)m[5] << 16), (u32)m[6] | ((u32)m[7] << 16));
    uint4 vl = make_uint4((u32)l[0] | ((u32)l[1] << 16), (u32)l[2] | ((u32)l[3] << 16),
                          (u32)l[4] | ((u32)l[5] << 16), (u32)l[6] | ((u32)l[7] << 16));
    *(uint4*)(out + o) = vh;
    *(uint4*)(out + ps + o) = vm;
    *(uint4*)(out + 2 * ps + o) = vl;
}

// dec_in[(l*B+b)][v] (3 planes) = split3(emb[caption[b][l]][v]), pad v>=300
__global__ __launch_bounds__(256)
void gather_split(const int* __restrict__ cap, const float* __restrict__ emb,
                  u16* __restrict__ out, size_t ps)
{
    int idx = blockIdx.x * 256 + threadIdx.x;
    if (idx >= 2560 * WVP_) return;
    int v = idx % WVP_;
    int r = idx / WVP_;
    int l = r >> 7, b = r & 127;
    float val = (v < WV_) ? emb[(size_t)cap[b * L_ + l] * WV_ + v] : 0.0f;
    u16 h, m, ll; split3(val, h, m, ll);
    out[idx] = h; out[idx + ps] = m; out[idx + 2 * ps] = ll;
}

// ---------- host ----------------------------------------------------------------
// Workspace map (MiB), peak 117 (< 120 verified-good in round 2):
//  [0,16)    XZ fp32 slab (8 steps x 128 x 4096)
//  [16,40)   WhE 3p
//  [40,52)   ACH 3p (frames chunk)
//  [52,100)  WXE 3p  -> after encoder: WhD 3p [52,76) | WXD 3p [76,83.5)
//                        | DECIN 3p [83.5,88.2) | WP 3p [88.2,90.5)
//  [100,115) HS 3p
//  [115,117) HB0 3p | HB1 3p | CB fp32
extern "C" void kernel_launch(void* const* d_in, const int* in_sizes, int n_in,
                              void* d_out, int out_size, void* d_ws, size_t ws_size,
                              hipStream_t stream)
{
    (void)in_sizes; (void)n_in; (void)out_size; (void)ws_size;
    const float* frames     = (const float*)d_in[0];
    const int*   caption    = (const int*)d_in[1];
    const float* embeddings = (const float*)d_in[2];
    const float* enc_kernel = (const float*)d_in[3];
    const float* enc_bias   = (const float*)d_in[4];
    const float* dec_kernel = (const float*)d_in[5];
    const float* dec_bias   = (const float*)d_in[6];
    const float* proj_W     = (const float*)d_in[7];
    const float* proj_b     = (const float*)d_in[8];
    float* out = (float*)d_out;

    char* base = (char*)d_ws;
    const size_t M1 = 1 << 20;
    const size_t WHP = (size_t)4096 * 1024;   // Wh plane elems
    const size_t ACHP = (size_t)1024 * 2048;
    const size_t WXEP = (size_t)4096 * 2048;
    const size_t WXDP = (size_t)4096 * 320;
    const size_t DECP = (size_t)2560 * 320;
    const size_t WPP  = (size_t)384 * 1024;
    const size_t HSP  = (size_t)2560 * 1024;
    const size_t HBP  = (size_t)128 * 1024;

    float* XZ  = (float*)(base);
    u16* WhE   = (u16*)(base + 16 * M1);
    u16* ACH   = (u16*)(base + 40 * M1);
    u16* WXE   = (u16*)(base + 52 * M1);
    u16* WhD   = (u16*)(base + 52 * M1);                       // overlay (post-enc)
    u16* WXD   = (u16*)((char*)WhD + 3 * WHP * 2);
    u16* DECIN = (u16*)((char*)WXD + 3 * WXDP * 2);
    u16* WP    = (u16*)((char*)DECIN + 3 * DECP * 2);
    u16* HS    = (u16*)(base + 100 * M1);
    u16* HB0   = (u16*)(base + 115 * M1);
    u16* HB1   = (u16*)((char*)HB0 + 3 * HBP * 2);
    float* CB  = (float*)((char*)HB1 + 3 * HBP * 2);

    // ---- encoder weight prep ----
    transpose_split<<<dim3(64, 128), 256, 0, stream>>>(enc_kernel, 4096, 0, 2048, 4096, WXE, 2048, WXEP);
    transpose_split<<<dim3(32, 128), 256, 0, stream>>>(enc_kernel, 4096, 2048, 1024, 4096, WhE, 1024, WHP);
    hipMemsetAsync(CB, 0, HBP * 4, stream);
    hipMemsetAsync(HB0, 0, 3 * HBP * 2, stream);

    u16* hb[2] = { HB0, HB1 };
    int cur = 0;

    // ---- encoder: 4 chunks of 8 timesteps ----
    for (int ch = 0; ch < 4; ++ch) {
        split_frames<<<1024, 256, 0, stream>>>(frames, ch * 8, ACH, ACHP);
        gemm6_tn<0><<<256, 256, 0, stream>>>(1024, 4096, 2048, 4096, 32,
            ACH, 2048, ACHP, WXE, 2048, WXEP, enc_bias, XZ, 4096);
        for (int tt = 0; tt < 8; ++tt) {
            lstm_step6<<<256, 256, 0, stream>>>(hb[cur], WhE, XZ + (size_t)tt * 128 * 4096,
                CB, hb[cur ^ 1], (u16*)nullptr);
            cur ^= 1;
        }
    }

    // ---- decoder weight prep (overlays WXE region; encoder GEMMs are done) ----
    transpose_split<<<dim3(32, 128), 256, 0, stream>>>(dec_kernel, 4096, 300, 1024, 4096, WhD, 1024, WHP);
    transpose_split<<<dim3(10, 128), 256, 0, stream>>>(dec_kernel, 4096, 0, 300, 4096, WXD, 320, WXDP);
    transpose_split<<<dim3(32, 12), 256, 0, stream>>>(proj_W, 300, 0, 1024, 300, WP, 1024, WPP);
    gather_split<<<(2560 * WVP_ + 255) / 256, 256, 0, stream>>>(caption, embeddings, DECIN, DECP);

    // ---- decoder: chunks of 8,8,4 steps ----
    int l = 0;
    for (int ch = 0; ch < 3; ++ch) {
        int nl = (ch == 2) ? 4 : 8;
        gemm6_tn<0><<<nl * 32, 256, 0, stream>>>(nl * 128, 4096, 320, 4096, 32,
            DECIN + (size_t)ch * 1024 * 320, 320, DECP, WXD, 320, WXDP, dec_bias, XZ, 4096);
        for (int q = 0; q < nl; ++q, ++l) {
            lstm_step6<<<256, 256, 0, stream>>>(hb[cur], WhD, XZ + (size_t)q * 128 * 4096,
                CB, hb[cur ^ 1], HS + (size_t)l * 128 * 1024);
            cur ^= 1;
        }
    }

    // ---- projection, scattered to [B][L][WV] ----
    gemm6_tn<1><<<60, 256, 0, stream>>>(2560, NPJ_, 1024, 300, 3,
        HS, 1024, HSP, WP, 1024, WPP, proj_b, out, 0);
}

// Round 10
// 1630.769 us; speedup vs baseline: 2.8231x; 1.0963x over previous
//
#include <hip/hip_runtime.h>
#include <math.h>

#define B_ 128
#define T_ 32
#define F_ 2048
#define H_ 1024
#define L_ 20
#define WV_ 300
#define WVP_ 320   // dec input K padded to mult of 32
#define NPJ_ 384   // proj N padded to mult of 128

typedef unsigned short u16;
typedef unsigned int u32;
typedef __attribute__((ext_vector_type(8))) short bf16x8;  // 8 bf16 = 4 VGPRs
typedef __attribute__((ext_vector_type(4))) float f32x4;

__device__ __forceinline__ u16 f2bf(float x) {
    union { float f; u32 u; } v; v.f = x;
    return (u16)((v.u + 0x7FFFu + ((v.u >> 16) & 1u)) >> 16);  // RNE
}
__device__ __forceinline__ float bf2f(u16 x) {
    union { u32 u; float f; } v; v.u = ((u32)x) << 16; return v.f;
}
// exact 3-term split: x = hi + mid + lo + r, |r| <= 2^-27 |x|
__device__ __forceinline__ void split3(float x, u16& h, u16& m, u16& l) {
    h = f2bf(x);  float r1 = x - bf2f(h);   // exact (Sterbenz)
    m = f2bf(r1); float r2 = r1 - bf2f(m);  // exact
    l = f2bf(r2);
}
__device__ __forceinline__ float sigf(float x) { return 1.0f / (1.0f + expf(-x)); }

__device__ __forceinline__ void g2lds16(const void* g, void* l) {
    __builtin_amdgcn_global_load_lds((const __attribute__((address_space(1))) void*)g,
                                     (__attribute__((address_space(3))) void*)l, 16, 0, 0);
}

// MFMA fragment read (16 rows x 32 k) from a [X][32]-u16 LDS tile with
// 16B-chunk XOR swizzle: byte = r*64 + ((chunk ^ ((r>>1)&3))<<4).
__device__ __forceinline__ bf16x8 fragld(const u16* tile, int rbase, int lane) {
    int r = rbase + (lane & 15);
    int byte = r * 64 + ((((lane >> 4) ^ (r >> 1)) & 3) << 4);
    return *(const bf16x8*)((const char*)tile + byte);
}

// stage slot s (16B) of a [rows][32]-u16 tile; src points at tile's first row
__device__ __forceinline__ void stage_tile(const u16* src, int row_stride, int k0,
                                           u16* lds, int s) {
    int row = s >> 2;
    int ch = (s & 3) ^ ((row >> 1) & 3);   // inverse swizzle on the GLOBAL side
    g2lds16(src + (size_t)row * row_stride + k0 + ch * 8, lds + (size_t)s * 8);
}

// ---------- split-bf16 TN GEMM: C = A @ Bt^T + bias ---------------------------
// A, Bt each up to 3 bf16 planes (plane strides aps/bps). 128x128 tile, 4 waves.
// NPASS=6: fp32-accurate (error ~2^-27/product). NPASS=3: ~2^-18, for use
// OUTSIDE the chaotic recurrence only (projection).
// 1-D grid; nb = bid % NB. For NB mult of 8 all M-blocks sharing a B-tile land
// on the same XCD -> B fetched once per chip. Double-buffered LDS prefetch.
// MODE_C: 0 = linear fp32 C[ldc]; 1 = proj scatter r=l*B+b -> out[b][l][col]
template<int MODE_C, int NPASS>
__global__ __launch_bounds__(256)
void gemm6_tn(int M, int N, int K, int Nreal, int NB,
              const u16* __restrict__ A, int lda, size_t aps,
              const u16* __restrict__ Bt, int ldb, size_t bps,
              const float* __restrict__ bias, float* __restrict__ C, int ldc)
{
    constexpr int NP = (NPASS == 6) ? 3 : 2;   // planes staged
    __shared__ u16 As[2][NP][128 * 32];
    __shared__ u16 Bs[2][NP][128 * 32];
    const int tid = threadIdx.x, lane = tid & 63, wid = tid >> 6;
    const int wr = wid >> 1, wc = wid & 1;
    const int bid = blockIdx.x;
    const int bm = (bid / NB) * 128, bn = (bid % NB) * 128;

    f32x4 acc[4][4] = {};
    const u16* Ar = A + (size_t)bm * lda;
    const u16* Br = Bt + (size_t)bn * ldb;

    auto STAGE = [&](int bsel, int k0) {
#pragma unroll
        for (int p = 0; p < NP; ++p) {
            stage_tile(Ar + p * aps, lda, k0, (u16*)As[bsel][p], tid);
            stage_tile(Ar + p * aps, lda, k0, (u16*)As[bsel][p], tid + 256);
            stage_tile(Br + p * bps, ldb, k0, (u16*)Bs[bsel][p], tid);
            stage_tile(Br + p * bps, ldb, k0, (u16*)Bs[bsel][p], tid + 256);
        }
    };

    const int KT = K >> 5;
    STAGE(0, 0);
    __syncthreads();
    for (int kt = 0; kt < KT; ++kt) {
        int pb = kt & 1;
        if (kt + 1 < KT) STAGE(pb ^ 1, (kt + 1) << 5);   // prefetch next k-tile
        bf16x8 af[NP][4];
#pragma unroll
        for (int p = 0; p < NP; ++p)
#pragma unroll
            for (int m = 0; m < 4; ++m) af[p][m] = fragld(As[pb][p], wr * 64 + m * 16, lane);
        // pass order small->large: (a0,b2) (a1,b1)(a0,b1) (a2,b0)(a1,b0)(a0,b0)
        if constexpr (NPASS == 6) {
            bf16x8 bf[4];
#pragma unroll
            for (int n = 0; n < 4; ++n) bf[n] = fragld(Bs[pb][2], wc * 64 + n * 16, lane);
#pragma unroll
            for (int m = 0; m < 4; ++m)
#pragma unroll
                for (int n = 0; n < 4; ++n)
                    acc[m][n] = __builtin_amdgcn_mfma_f32_16x16x32_bf16(af[0][m], bf[n], acc[m][n], 0, 0, 0);
        }
        {
            bf16x8 bf[4];
#pragma unroll
            for (int n = 0; n < 4; ++n) bf[n] = fragld(Bs[pb][1], wc * 64 + n * 16, lane);
            if constexpr (NPASS == 6) {
#pragma unroll
                for (int m = 0; m < 4; ++m)
#pragma unroll
                    for (int n = 0; n < 4; ++n)
                        acc[m][n] = __builtin_amdgcn_mfma_f32_16x16x32_bf16(af[1][m], bf[n], acc[m][n], 0, 0, 0);
            }
#pragma unroll
            for (int m = 0; m < 4; ++m)
#pragma unroll
                for (int n = 0; n < 4; ++n)
                    acc[m][n] = __builtin_amdgcn_mfma_f32_16x16x32_bf16(af[0][m], bf[n], acc[m][n], 0, 0, 0);
        }
        {
            bf16x8 bf[4];
#pragma unroll
            for (int n = 0; n < 4; ++n) bf[n] = fragld(Bs[pb][0], wc * 64 + n * 16, lane);
            if constexpr (NPASS == 6) {
#pragma unroll
                for (int m = 0; m < 4; ++m)
#pragma unroll
                    for (int n = 0; n < 4; ++n)
                        acc[m][n] = __builtin_amdgcn_mfma_f32_16x16x32_bf16(af[2][m], bf[n], acc[m][n], 0, 0, 0);
            }
#pragma unroll
            for (int m = 0; m < 4; ++m)
#pragma unroll
                for (int n = 0; n < 4; ++n)
                    acc[m][n] = __builtin_amdgcn_mfma_f32_16x16x32_bf16(af[1][m], bf[n], acc[m][n], 0, 0, 0);
#pragma unroll
            for (int m = 0; m < 4; ++m)
#pragma unroll
                for (int n = 0; n < 4; ++n)
                    acc[m][n] = __builtin_amdgcn_mfma_f32_16x16x32_bf16(af[0][m], bf[n], acc[m][n], 0, 0, 0);
        }
        __syncthreads();   // waits prefetch (vmcnt) + all waves done with buffer pb
    }

    // C/D layout: col = lane&15, row = (lane>>4)*4 + reg   [m89-verified]
    const int rq = (lane >> 4) << 2;
    const int cl = lane & 15;
#pragma unroll
    for (int m = 0; m < 4; ++m) {
        int grow = bm + wr * 64 + m * 16 + rq;
#pragma unroll
        for (int n = 0; n < 4; ++n) {
            int gcol = bn + wc * 64 + n * 16 + cl;
            if (gcol < Nreal) {
                float bv = bias ? bias[gcol] : 0.0f;
#pragma unroll
                for (int r = 0; r < 4; ++r) {
                    float v = acc[m][n][r] + bv;
                    int rr = grow + r;
                    if (MODE_C == 0) {
                        C[(size_t)rr * ldc + gcol] = v;
                    } else {
                        int l = rr >> 7, b = rr & 127;
                        C[((size_t)b * L_ + l) * WV_ + gcol] = v;
                    }
                }
            }
        }
    }
}

// ---------- fused recurrent step, 6-pass, v4 ----------------------------------
// grid 512: blk&127 = 8-wide h-tile, blk>>7 = 32-row quarter -> 2 blocks/CU so
// one block's staging overlaps the other's MFMA (m114 implicit overlap).
// XCD affinity: ht sharers at blk distance 128 (== 0 mod 8) -> same XCD; per-XCD
// L2 working set ~2.9 MB < 4 MB.
// Output per block: 32 rows x 8 h-cols (32 gate-cols). 4 waves, 1 MFMA tile each
// (wave w: m = w>>1 row-halves, n = w&1 gate-col-halves).
// BK=64: 2 sub-tiles/buffer, ascending k -> arithmetic bitwise identical to v2/v3.
// Per-sub-tile layout (768 slots): A planes p=0..2 [32r][32k] (128 slots each),
// then B planes p=0..2 [32r][32k] (128 slots each); B row r = gate(r>>3), col (r&7).
__global__ __launch_bounds__(256)
void lstm_step6(const u16* __restrict__ hp,   // 3p [128][1024] bf16
                const u16* __restrict__ WhT,  // 3p [4096][1024] bf16 (transposed)
                const float* __restrict__ xz, // [128][4096] fp32 (this step)
                float* __restrict__ c,        // [128][1024] fp32 (in-place)
                u16* __restrict__ hop,        // 3p [128][1024] out
                u16* __restrict__ hsp)        // 3p [2560][1024] out, nullable
{
    const size_t HP = 128 * 1024, WHP = (size_t)4096 * 1024, HSP = (size_t)2560 * 1024;
    __shared__ u16 stg[2][12288];  // 2 buf x 2 subtiles x 768 slots x 16B = 48 KB
    __shared__ float zs[32 * 36];
    const int tid = threadIdx.x, lane = tid & 63, w = tid >> 6;
    const int ht = blockIdx.x & 127, q = blockIdx.x >> 7;
    const int r0 = q * 32;
    const int h0 = ht * 8;

    f32x4 acc = {};

    auto STAGE = [&](int bsel, int k0) {   // stages 64 k (2 sub-tiles, 1536 slots)
        u16* dstb = &stg[bsel][0];
#pragma unroll
        for (int j = 0; j < 6; ++j) {
            int s = tid + j * 256;          // s in [0, 1536)
            int sub = (s >= 768) ? 1 : 0;
            int s2 = s - sub * 768;
            int kk = k0 + sub * 32;
            u16* dst = dstb + s * 8;
            if (s2 < 384) {
                int p = s2 >> 7, l = s2 & 127, row = l >> 2;
                int ch = (l & 3) ^ ((row >> 1) & 3);
                g2lds16(hp + (size_t)p * HP + (size_t)(r0 + row) * 1024 + kk + ch * 8, dst);
            } else {
                int t2 = s2 - 384;
                int p = t2 >> 7, l = t2 & 127, row = l >> 2;
                int ch = (l & 3) ^ ((row >> 1) & 3);
                int wrow = (row >> 3) * 1024 + h0 + (row & 7);   // gate*1024 + h0 + col
                g2lds16(WhT + (size_t)p * WHP + (size_t)wrow * 1024 + kk + ch * 8, dst);
            }
        }
    };

    const int mrow = (w >> 1) * 16;   // A fragment row base
    const int nrow = (w & 1) * 16;    // B fragment row base

    STAGE(0, 0);
    __syncthreads();
    for (int t = 0; t < 16; ++t) {
        int pb = t & 1;
        if (t < 15) STAGE(pb ^ 1, (t + 1) * 64);   // prefetch next 64-k tile
#pragma unroll
        for (int sub = 0; sub < 2; ++sub) {
            const u16* sb = &stg[pb][sub * 6144];
            bf16x8 a[3], bfr[3];
#pragma unroll
            for (int p = 0; p < 3; ++p) {
                a[p] = fragld(sb + p * 1024, mrow, lane);
                bfr[p] = fragld(sb + 3072 + p * 1024, nrow, lane);
            }
            // small->large: (a0,b2) (a1,b1) (a0,b1) (a2,b0) (a1,b0) (a0,b0)
            acc = __builtin_amdgcn_mfma_f32_16x16x32_bf16(a[0], bfr[2], acc, 0, 0, 0);
            acc = __builtin_amdgcn_mfma_f32_16x16x32_bf16(a[1], bfr[1], acc, 0, 0, 0);
            acc = __builtin_amdgcn_mfma_f32_16x16x32_bf16(a[0], bfr[1], acc, 0, 0, 0);
            acc = __builtin_amdgcn_mfma_f32_16x16x32_bf16(a[2], bfr[0], acc, 0, 0, 0);
            acc = __builtin_amdgcn_mfma_f32_16x16x32_bf16(a[1], bfr[0], acc, 0, 0, 0);
            acc = __builtin_amdgcn_mfma_f32_16x16x32_bf16(a[0], bfr[0], acc, 0, 0, 0);
        }
        __syncthreads();   // waits prefetch (vmcnt) + all waves done with buffer pb
    }

    {   // acc -> zs[32][36]; C/D layout col=lane&15, row=(lane>>4)*4+reg
        int zr = (w >> 1) * 16 + ((lane >> 4) << 2);
        int zc = (w & 1) * 16 + (lane & 15);
#pragma unroll
        for (int r = 0; r < 4; ++r)
            zs[(zr + r) * 36 + zc] = acc[r];
    }
    __syncthreads();

    {   // cell: 32 rows x 8 h-cols, 1 elem/thread; all fp32
        int row = tid >> 3;
        int hc = tid & 7;
        int b = r0 + row;
        int h = h0 + hc;
        const float* xzr = xz + (size_t)b * 4096;
        float zi = zs[row * 36 + 0  + hc] + xzr[h];
        float zj = zs[row * 36 + 8  + hc] + xzr[1024 + h];
        float zf = zs[row * 36 + 16 + hc] + xzr[2048 + h];
        float zo = zs[row * 36 + 24 + hc] + xzr[3072 + h];
        float cv = c[(size_t)b * 1024 + h];
        float cc = cv * sigf(zf + 1.0f) + sigf(zi) * tanhf(zj);
        float hn = tanhf(cc) * sigf(zo);
        u16 ph, pm, pl;
        split3(hn, ph, pm, pl);
        c[(size_t)b * 1024 + h] = cc;
        size_t o = (size_t)b * 1024 + h;
        hop[o] = ph; hop[HP + o] = pm; hop[2 * HP + o] = pl;
        if (hsp) { hsp[o] = ph; hsp[HSP + o] = pm; hsp[2 * HSP + o] = pl; }
    }
}

// ---------- conversion / split kernels ----------------------------------------
// out[n][k] (3 planes) = split3(in[in_row0+k][n]), zero-padded over grid range
__global__ __launch_bounds__(256)
void transpose_split(const float* __restrict__ in, int ldin, int in_row0,
                     int K_in, int N_in, u16* __restrict__ out, int ldout, size_t ps)
{
    __shared__ float tl[32][33];
    const int tid = threadIdx.x;
    const int k0 = blockIdx.x * 32, n0 = blockIdx.y * 32;
    const int cc = tid & 31, rr = tid >> 5;
#pragma unroll
    for (int p = 0; p < 4; ++p) {
        int r = rr + p * 8;
        int k = k0 + r, n = n0 + cc;
        tl[r][cc] = (k < K_in && n < N_in) ? in[(size_t)(in_row0 + k) * ldin + n] : 0.0f;
    }
    __syncthreads();
#pragma unroll
    for (int p = 0; p < 4; ++p) {
        int nr = rr + p * 8;
        u16 h, m, l; split3(tl[cc][nr], h, m, l);
        size_t o = (size_t)(n0 + nr) * ldout + k0 + cc;
        out[o] = h; out[o + ps] = m; out[o + 2 * ps] = l;
    }
}

// frames chunk: rows rr in [0,1024), t = t0 + rr/128, b = rr%128 -> 3 planes [1024][2048]
__global__ __launch_bounds__(256)
void split_frames(const float* __restrict__ fr, int t0, u16* __restrict__ out, size_t ps)
{
    int row = blockIdx.x;
    int t = t0 + (row >> 7), b = row & 127;
    const float* src = fr + ((size_t)b * T_ + t) * F_;
    int off = threadIdx.x * 8;
    float4 v0 = *(const float4*)(src + off);
    float4 v1 = *(const float4*)(src + off + 4);
    float x[8] = {v0.x, v0.y, v0.z, v0.w, v1.x, v1.y, v1.z, v1.w};
    u16 h[8], m[8], l[8];
#pragma unroll
    for (int q = 0; q < 8; ++q) split3(x[q], h[q], m[q], l[q]);
    size_t o = (size_t)row * F_ + off;
    uint4 vh = make_uint4((u32)h[0] | ((u32)h[1] << 16), (u32)h[2] | ((u32)h[3] << 16),
                          (u32)h[4] | ((u32)h[5] << 16), (u32)h[6] | ((u32)h[7] << 16));
    uint4 vm = make_uint4((u32)m[0] | ((u32)m[1] << 16), (u32)m[2] | ((u32)m[3] << 16),
                          (u32)m[4] | ((u32)m[5] << 16), (u32)m[6] | ((u32)m[7] << 16));
    uint4 vl = make_uint4((u32)l[0] | ((u32)l[1] << 16), (u32)l[2] | ((u32)l[3] << 16),
                          (u32)l[4] | ((u32)l[5] << 16), (u32)l[6] | ((u32)l[7] << 16));
    *(uint4*)(out + o) = vh;
    *(uint4*)(out + ps + o) = vm;
    *(uint4*)(out + 2 * ps + o) = vl;
}

// dec_in[(l*B+b)][v] (3 planes) = split3(emb[caption[b][l]][v]), pad v>=300
__global__ __launch_bounds__(256)
void gather_split(const int* __restrict__ cap, const float* __restrict__ emb,
                  u16* __restrict__ out, size_t ps)
{
    int idx = blockIdx.x * 256 + threadIdx.x;
    if (idx >= 2560 * WVP_) return;
    int v = idx % WVP_;
    int r = idx / WVP_;
    int l = r >> 7, b = r & 127;
    float val = (v < WV_) ? emb[(size_t)cap[b * L_ + l] * WV_ + v] : 0.0f;
    u16 h, m, ll; split3(val, h, m, ll);
    out[idx] = h; out[idx + ps] = m; out[idx + 2 * ps] = ll;
}

// ---------- host ----------------------------------------------------------------
// Workspace map (MiB), peak 117 (< 120 verified-good in round 2):
//  [0,16)    XZ fp32 slab (8 steps x 128 x 4096)
//  [16,40)   WhE 3p
//  [40,52)   ACH 3p (frames chunk)
//  [52,100)  WXE 3p  -> after encoder: WhD 3p [52,76) | WXD 3p [76,83.5)
//                        | DECIN 3p [83.5,88.2) | WP 3p [88.2,90.5)
//  [100,115) HS 3p
//  [115,117) HB0 3p | HB1 3p | CB fp32
extern "C" void kernel_launch(void* const* d_in, const int* in_sizes, int n_in,
                              void* d_out, int out_size, void* d_ws, size_t ws_size,
                              hipStream_t stream)
{
    (void)in_sizes; (void)n_in; (void)out_size; (void)ws_size;
    const float* frames     = (const float*)d_in[0];
    const int*   caption    = (const int*)d_in[1];
    const float* embeddings = (const float*)d_in[2];
    const float* enc_kernel = (const float*)d_in[3];
    const float* enc_bias   = (const float*)d_in[4];
    const float* dec_kernel = (const float*)d_in[5];
    const float* dec_bias   = (const float*)d_in[6];
    const float* proj_W     = (const float*)d_in[7];
    const float* proj_b     = (const float*)d_in[8];
    float* out = (float*)d_out;

    char* base = (char*)d_ws;
    const size_t M1 = 1 << 20;
    const size_t WHP = (size_t)4096 * 1024;   // Wh plane elems
    const size_t ACHP = (size_t)1024 * 2048;
    const size_t WXEP = (size_t)4096 * 2048;
    const size_t WXDP = (size_t)4096 * 320;
    const size_t DECP = (size_t)2560 * 320;
    const size_t WPP  = (size_t)384 * 1024;
    const size_t HSP  = (size_t)2560 * 1024;
    const size_t HBP  = (size_t)128 * 1024;

    float* XZ  = (float*)(base);
    u16* WhE   = (u16*)(base + 16 * M1);
    u16* ACH   = (u16*)(base + 40 * M1);
    u16* WXE   = (u16*)(base + 52 * M1);
    u16* WhD   = (u16*)(base + 52 * M1);                       // overlay (post-enc)
    u16* WXD   = (u16*)((char*)WhD + 3 * WHP * 2);
    u16* DECIN = (u16*)((char*)WXD + 3 * WXDP * 2);
    u16* WP    = (u16*)((char*)DECIN + 3 * DECP * 2);
    u16* HS    = (u16*)(base + 100 * M1);
    u16* HB0   = (u16*)(base + 115 * M1);
    u16* HB1   = (u16*)((char*)HB0 + 3 * HBP * 2);
    float* CB  = (float*)((char*)HB1 + 3 * HBP * 2);

    // ---- encoder weight prep ----
    transpose_split<<<dim3(64, 128), 256, 0, stream>>>(enc_kernel, 4096, 0, 2048, 4096, WXE, 2048, WXEP);
    transpose_split<<<dim3(32, 128), 256, 0, stream>>>(enc_kernel, 4096, 2048, 1024, 4096, WhE, 1024, WHP);
    hipMemsetAsync(CB, 0, HBP * 4, stream);
    hipMemsetAsync(HB0, 0, 3 * HBP * 2, stream);

    u16* hb[2] = { HB0, HB1 };
    int cur = 0;

    // ---- encoder: 4 chunks of 8 timesteps ----
    for (int ch = 0; ch < 4; ++ch) {
        split_frames<<<1024, 256, 0, stream>>>(frames, ch * 8, ACH, ACHP);
        gemm6_tn<0, 6><<<256, 256, 0, stream>>>(1024, 4096, 2048, 4096, 32,
            ACH, 2048, ACHP, WXE, 2048, WXEP, enc_bias, XZ, 4096);
        for (int tt = 0; tt < 8; ++tt) {
            lstm_step6<<<512, 256, 0, stream>>>(hb[cur], WhE, XZ + (size_t)tt * 128 * 4096,
                CB, hb[cur ^ 1], (u16*)nullptr);
            cur ^= 1;
        }
    }

    // ---- decoder weight prep (overlays WXE region; encoder GEMMs are done) ----
    transpose_split<<<dim3(32, 128), 256, 0, stream>>>(dec_kernel, 4096, 300, 1024, 4096, WhD, 1024, WHP);
    transpose_split<<<dim3(10, 128), 256, 0, stream>>>(dec_kernel, 4096, 0, 300, 4096, WXD, 320, WXDP);
    transpose_split<<<dim3(32, 12), 256, 0, stream>>>(proj_W, 300, 0, 1024, 300, WP, 1024, WPP);
    gather_split<<<(2560 * WVP_ + 255) / 256, 256, 0, stream>>>(caption, embeddings, DECIN, DECP);

    // ---- decoder: chunks of 8,8,4 steps ----
    int l = 0;
    for (int ch = 0; ch < 3; ++ch) {
        int nl = (ch == 2) ? 4 : 8;
        gemm6_tn<0, 6><<<nl * 32, 256, 0, stream>>>(nl * 128, 4096, 320, 4096, 32,
            DECIN + (size_t)ch * 1024 * 320, 320, DECP, WXD, 320, WXDP, dec_bias, XZ, 4096);
        for (int q = 0; q < nl; ++q, ++l) {
            lstm_step6<<<512, 256, 0, stream>>>(hb[cur], WhD, XZ + (size_t)q * 128 * 4096,
                CB, hb[cur ^ 1], HS + (size_t)l * 128 * 1024);
            cur ^= 1;
        }
    }

    // ---- projection, scattered to [B][L][WV] (3-pass: outside the recurrence,
    //      dropped terms add ~6e-5 direct error only) ----
    gemm6_tn<1, 3><<<60, 256, 0, stream>>>(2560, NPJ_, 1024, 300, 3,
        HS, 1024, HSP, WP, 1024, WPP, proj_b, out, 0);
}